// Round 7
// baseline (594.662 us; speedup 1.0000x reference)
//
#include <hip/hip_runtime.h>
#include <hip/hip_bf16.h>

#define N_NODES 8192
#define IN_FEAT 256
#define OUT_F   64
#define NHEAD   4
#define HF      256     // NHEAD*OUT_F
#define NEG     0.2f

typedef unsigned short u16;
typedef __attribute__((ext_vector_type(8))) short short8;   // 8 bf16 (4 VGPRs)
typedef __attribute__((ext_vector_type(4))) float f32x4;    // MFMA C/D

__device__ __forceinline__ u16 f2bf(float f) {
    union { unsigned int u; float f; } v; v.f = f;
    unsigned int r = v.u + 0x7FFFu + ((v.u >> 16) & 1u);  // RNE
    return (u16)(r >> 16);
}

// ---------------------------------------------------------------------------
// K0: PWT[k][c] = PW[c][k]  (256x256 fp32 transpose)
// ---------------------------------------------------------------------------
__global__ __launch_bounds__(256) void k_tr(const float* __restrict__ PW,
                                            float* __restrict__ PWT) {
    __shared__ float t[64][65];
    const int bx = (blockIdx.x & 3) * 64;   // k tile
    const int by = (blockIdx.x >> 2) * 64;  // c tile
    const int tx = threadIdx.x & 63;
    const int ty = threadIdx.x >> 6;
    #pragma unroll
    for (int r = ty; r < 64; r += 4)
        t[r][tx] = PW[(size_t)(by + r) * IN_FEAT + bx + tx];
    __syncthreads();
    #pragma unroll
    for (int r = ty; r < 64; r += 4)
        PWT[(size_t)(bx + r) * HF + by + tx] = t[tx][r];
}

// ---------------------------------------------------------------------------
// K1: per 4 rows: support = X@W -> suppT (bf16 [H*64][N]), f1/f2 head dots,
//     proj = X@PWT + proj_b + bias -> d_out. FUSED TAIL: zero anum/aden and
//     bit-pack this block's 4 adjacency rows (adj stream overlaps compute;
//     removes the serial k_bits dispatch).
// ---------------------------------------------------------------------------
#define RPB 4
__global__ __launch_bounds__(256, 8) void k_gemm(
    const float* __restrict__ inp,   // [N, 256]
    const float* __restrict__ W,     // [256, 256] (k-major rows)
    const float* __restrict__ U,     // [H*64] flat
    const float* __restrict__ V,     // [H*64] flat
    const float* __restrict__ Bias,  // [256]
    const float* __restrict__ PWT,   // [256 k][256 c]
    const float* __restrict__ PB,    // [256]
    const float* __restrict__ adj,   // [N, N] fp32
    u16*   __restrict__ suppT,       // [H*64][N] bf16 (feature-major)
    float* __restrict__ f1,          // [H][N]
    float* __restrict__ f2,          // [H][N]
    float* __restrict__ outp,        // [N][256]  proj + bias + proj_b
    u16*   __restrict__ gb,          // [N][1024] nibble flags
    float* __restrict__ anum,        // [N][256]  zeroed here
    float* __restrict__ aden)        // [H][N]    zeroed here
{
    __shared__ __align__(16) float in_lds[RPB][IN_FEAT];
    const int c  = threadIdx.x;            // output column 0..255
    const int n0 = blockIdx.x * RPB;

    #pragma unroll
    for (int r = 0; r < RPB; ++r)
        in_lds[r][c] = inp[(size_t)(n0 + r) * IN_FEAT + c];
    __syncthreads();

    float accs[RPB], accp[RPB];
    #pragma unroll
    for (int r = 0; r < RPB; ++r) { accs[r] = 0.f; accp[r] = 0.f; }

    const float* wc = W   + c;
    const float* pc = PWT + c;
    float w0 = wc[0 * HF], w1 = wc[1 * HF], w2 = wc[2 * HF], w3 = wc[3 * HF];
    float p0 = pc[0 * HF], p1 = pc[1 * HF], p2 = pc[2 * HF], p3 = pc[3 * HF];

    #pragma unroll 1
    for (int k = 0; k < IN_FEAT; k += 4) {
        const int kn = (k + 4) & 255;          // wrap: last prefetch discarded
        const float nw0 = wc[(kn + 0) * HF];
        const float nw1 = wc[(kn + 1) * HF];
        const float nw2 = wc[(kn + 2) * HF];
        const float nw3 = wc[(kn + 3) * HF];
        const float np0 = pc[(kn + 0) * HF];
        const float np1 = pc[(kn + 1) * HF];
        const float np2 = pc[(kn + 2) * HF];
        const float np3 = pc[(kn + 3) * HF];
        #pragma unroll
        for (int r = 0; r < RPB; ++r) {
            const float4 xv = *(const float4*)&in_lds[r][k];
            accs[r] = fmaf(xv.x, w0, accs[r]);
            accs[r] = fmaf(xv.y, w1, accs[r]);
            accs[r] = fmaf(xv.z, w2, accs[r]);
            accs[r] = fmaf(xv.w, w3, accs[r]);
            accp[r] = fmaf(xv.x, p0, accp[r]);
            accp[r] = fmaf(xv.y, p1, accp[r]);
            accp[r] = fmaf(xv.z, p2, accp[r]);
            accp[r] = fmaf(xv.w, p3, accp[r]);
        }
        w0 = nw0; w1 = nw1; w2 = nw2; w3 = nw3;
        p0 = np0; p1 = np1; p2 = np2; p3 = np3;
    }

    const int h = c >> 6, lane = c & 63;
    const float uv = U[c], vv = V[c];
    const float bb = Bias[c] + PB[c];

    union { short s[4]; unsigned long long q; } sv;
    #pragma unroll
    for (int r = 0; r < RPB; ++r) sv.s[r] = (short)f2bf(accs[r]);
    *(unsigned long long*)(suppT + (size_t)c * N_NODES + n0) = sv.q;

    #pragma unroll
    for (int r = 0; r < RPB; ++r) {
        float s1 = accs[r] * uv, s2 = accs[r] * vv;
        #pragma unroll
        for (int mm = 32; mm > 0; mm >>= 1) {
            s1 += __shfl_xor(s1, mm);
            s2 += __shfl_xor(s2, mm);
        }
        if (lane == 0) {
            f1[h * N_NODES + n0 + r] = s1;
            f2[h * N_NODES + n0 + r] = s2;
        }
        outp[(size_t)(n0 + r) * HF + c] = accp[r] + bb;
    }

    // ---- fused tail: zero attn accumulators ----
    #pragma unroll
    for (int r = 0; r < RPB; ++r)
        anum[(size_t)(n0 + r) * HF + c] = 0.f;
    if (c < 16)
        aden[(size_t)(c >> 2) * N_NODES + n0 + (c & 3)] = 0.f;

    // ---- fused tail: pack adjacency rows n0..n0+3 into nibble flags ----
    // word w covers j=8w..8w+7: bits 0..3 = j..j+3, bits 8..11 = j+4..j+7
    #pragma unroll
    for (int r = 0; r < RPB; ++r) {
        const float* ar = adj + (size_t)(n0 + r) * N_NODES;
        u16* gr = gb + (size_t)(n0 + r) * 1024;
        #pragma unroll
        for (int pass = 0; pass < 4; ++pass) {
            const int w = pass * 256 + c;
            const float4 a0 = *(const float4*)(ar + w * 8);
            const float4 a1 = *(const float4*)(ar + w * 8 + 4);
            gr[w] = (u16)(
                (unsigned)(a0.x != 0.f)        | ((unsigned)(a0.y != 0.f) << 1) |
                ((unsigned)(a0.z != 0.f) << 2) | ((unsigned)(a0.w != 0.f) << 3) |
                ((unsigned)(a1.x != 0.f) << 8) | ((unsigned)(a1.y != 0.f) << 9) |
                ((unsigned)(a1.z != 0.f) << 10)| ((unsigned)(a1.w != 0.f) << 11));
        }
    }
}

// ---------------------------------------------------------------------------
// K2: per-head f1 max + factored-exponential tables:
//     EA[h][j] = exp(f1j - f1max), EB[h][j] = exp(0.2*(f1j - f1max))
// ---------------------------------------------------------------------------
__global__ __launch_bounds__(256) void k_prep(const float* __restrict__ f1,
                                              float* __restrict__ f1max,
                                              float* __restrict__ EA,
                                              float* __restrict__ EB) {
    __shared__ float red[256];
    const int h = blockIdx.x;
    float m = -1e30f;
    for (int j = threadIdx.x; j < N_NODES; j += 256)
        m = fmaxf(m, f1[h * N_NODES + j]);
    red[threadIdx.x] = m;
    __syncthreads();
    for (int s = 128; s > 0; s >>= 1) {
        if (threadIdx.x < s) red[threadIdx.x] = fmaxf(red[threadIdx.x], red[threadIdx.x + s]);
        __syncthreads();
    }
    const float fm = red[0];
    if (threadIdx.x == 0) f1max[h] = fm;
    for (int j = threadIdx.x; j < N_NODES; j += 256) {
        const float d = f1[h * N_NODES + j] - fm;
        EA[h * N_NODES + j] = __expf(d);
        EB[h * N_NODES + j] = __expf(NEG * d);
    }
}

// ---------------------------------------------------------------------------
// K3: MFMA attention, TI=64 / 4 i-subtiles per wave (4x B+EA/EB reuse ->
//   halves L2 traffic vs TI=32). Grid 512 = 128 i-tiles x 4 j-windows;
//   block = 256 thr = 4 waves = 4 heads. NO LDS, NO barriers: flags come
//   straight from L1/L2-resident gbits (8 KB/block working set), partials
//   combine via float atomics into anum/aden (zeroed by k_gemm).
//   Flag masking is 3 int ops (bfe/sub/and), no vcc chains.
// ---------------------------------------------------------------------------
#define TI 64
#define NSUB 4
#define JSPLIT_G 4
#define JW (N_NODES / JSPLIT_G)     // 2048-j window per block

__global__ __launch_bounds__(256, 3) void k_attn_mfma(
    const u16* __restrict__ gbits,   // [N][1024] nibble flags
    const u16* __restrict__ suppT,   // [H*64][N] bf16 (feature-major)
    const float* __restrict__ EA,    // [H][N] exp(f1 - f1max)
    const float* __restrict__ EB,    // [H][N] exp(0.2*(f1 - f1max))
    const float* __restrict__ f2,    // [H][N]
    const float* __restrict__ f1max, // [H]
    float* __restrict__ anum,        // [N][256] numerator accumulator
    float* __restrict__ aden)        // [H][N]   denominator accumulator
{
    const int itile = blockIdx.x >> 2;       // 0..127
    const int jwin  = blockIdx.x & 3;        // j-window
    const int i0    = itile * TI;
    const int J0    = jwin * JW;
    const int h     = threadIdx.x >> 6;      // wave = head
    const int lane  = threadIdx.x & 63;
    const int col   = lane & 15;             // m (A) / n (B) / col (C)
    const int quad  = lane >> 4;

    const float fm = f1max[h];
    float CA[NSUB], CB[NSUB], ls[NSUB];
    #pragma unroll
    for (int s = 0; s < NSUB; ++s) {
        const float f2i = f2[(size_t)h * N_NODES + i0 + s * 16 + col];
        const float g  = fm + f2i;
        const float mi = fmaxf(g, NEG * g);                 // leaky(g)
        CA[s] = __expf(g - mi);
        CB[s] = __expf(NEG * g - mi);
        ls[s] = 0.f;
    }

    const float* EAh = EA + (size_t)h * N_NODES + J0;
    const float* EBh = EB + (size_t)h * N_NODES + J0;
    const u16*   bt  = suppT + (size_t)((h << 6) + col) * N_NODES + J0;
    const u16*   gp  = gbits + (size_t)(i0 + col) * 1024 + (J0 >> 3);

    f32x4 acc[NSUB][4];
    #pragma unroll
    for (int s = 0; s < NSUB; ++s)
        #pragma unroll
        for (int t = 0; t < 4; ++t)
            acc[s][t] = (f32x4){0.f, 0.f, 0.f, 0.f};

    const int qo = quad << 3;

    #pragma unroll 1
    for (int jb = 0; jb < JW; jb += 32) {
        const int jl = jb + qo;                             // lane's local j
        const short8 bv0 = *(const short8*)(bt + (size_t)0 * 16 * N_NODES + jl);
        const short8 bv1 = *(const short8*)(bt + (size_t)1 * 16 * N_NODES + jl);
        const short8 bv2 = *(const short8*)(bt + (size_t)2 * 16 * N_NODES + jl);
        const short8 bv3 = *(const short8*)(bt + (size_t)3 * 16 * N_NODES + jl);
        const float4 ea0 = *(const float4*)(EAh + jl);
        const float4 ea1 = *(const float4*)(EAh + jl + 4);
        const float4 eb0 = *(const float4*)(EBh + jl);
        const float4 eb1 = *(const float4*)(EBh + jl + 4);
        const int wo = (jb >> 3) + quad;                    // flag word offset
        u16 gw[NSUB];
        #pragma unroll
        for (int s = 0; s < NSUB; ++s) gw[s] = gp[s * 16384 + wo];

        const float eav[8] = {ea0.x, ea0.y, ea0.z, ea0.w, ea1.x, ea1.y, ea1.z, ea1.w};
        const float ebv[8] = {eb0.x, eb0.y, eb0.z, eb0.w, eb1.x, eb1.y, eb1.z, eb1.w};

        #pragma unroll
        for (int s = 0; s < NSUB; ++s) {
            union { short8 v; unsigned w[4]; } af;
            #pragma unroll
            for (int p = 0; p < 4; ++p) {
                const int je = 2 * p, jo = 2 * p + 1;
                const int she = (je & 3) + ((je >> 2) << 3);
                const int sho = (jo & 3) + ((jo >> 2) << 3);
                float xe = fmaxf(eav[je] * CA[s], ebv[je] * CB[s]);
                float xo = fmaxf(eav[jo] * CA[s], ebv[jo] * CB[s]);
                const unsigned me = 0u - ((unsigned)(gw[s] >> she) & 1u);
                const unsigned mo = 0u - ((unsigned)(gw[s] >> sho) & 1u);
                xe = __uint_as_float(__float_as_uint(xe) & me);
                xo = __uint_as_float(__float_as_uint(xo) & mo);
                ls[s] += xe;
                ls[s] += xo;
                asm("v_cvt_pk_bf16_f32 %0, %1, %2"
                    : "=v"(af.w[p]) : "v"(xe), "v"(xo));
            }
            acc[s][0] = __builtin_amdgcn_mfma_f32_16x16x32_bf16(af.v, bv0, acc[s][0], 0, 0, 0);
            acc[s][1] = __builtin_amdgcn_mfma_f32_16x16x32_bf16(af.v, bv1, acc[s][1], 0, 0, 0);
            acc[s][2] = __builtin_amdgcn_mfma_f32_16x16x32_bf16(af.v, bv2, acc[s][2], 0, 0, 0);
            acc[s][3] = __builtin_amdgcn_mfma_f32_16x16x32_bf16(af.v, bv3, acc[s][3], 0, 0, 0);
        }
    }

    // denominators: reduce over quads; then every lane holds sum for i=lane&15
    #pragma unroll
    for (int s = 0; s < NSUB; ++s) {
        ls[s] += __shfl_xor(ls[s], 16);
        ls[s] += __shfl_xor(ls[s], 32);
    }
    if (quad == 0) {
        #pragma unroll
        for (int s = 0; s < NSUB; ++s)
            unsafeAtomicAdd(aden + (size_t)h * N_NODES + i0 + s * 16 + col, ls[s]);
    }

    // numerators: C layout col=lane&15, row=quad*4+reg
    #pragma unroll
    for (int s = 0; s < NSUB; ++s) {
        #pragma unroll
        for (int reg = 0; reg < 4; ++reg) {
            const int irow = (quad << 2) + reg;
            float* ap = anum + (size_t)(i0 + s * 16 + irow) * HF + (h << 6) + col;
            #pragma unroll
            for (int t = 0; t < 4; ++t)
                unsafeAtomicAdd(ap + (t << 4), acc[s][t][reg]);
        }
    }
}

// ---------------------------------------------------------------------------
// K4: out += anum / aden   (denominator > 0 guaranteed by self-loops)
// ---------------------------------------------------------------------------
__global__ __launch_bounds__(256) void k_fin(const float* __restrict__ anum,
                                             const float* __restrict__ aden,
                                             float* __restrict__ out) {
    const int c = threadIdx.x;
    const int h = c >> 6;
    #pragma unroll
    for (int rr = 0; rr < 4; ++rr) {
        const int n = blockIdx.x * 4 + rr;
        out[(size_t)n * HF + c] += anum[(size_t)n * HF + c]
                                 / aden[(size_t)h * N_NODES + n];
    }
}

// ---------------------------------------------------------------------------
extern "C" void kernel_launch(void* const* d_in, const int* in_sizes, int n_in,
                              void* d_out, int out_size, void* d_ws, size_t ws_size,
                              hipStream_t stream) {
    const float* inp  = (const float*)d_in[0];  // [8192,256]
    const float* adj  = (const float*)d_in[1];  // [8192,8192]
    const float* W    = (const float*)d_in[2];  // [256,256]
    const float* U    = (const float*)d_in[3];  // [4,64,1]
    const float* V    = (const float*)d_in[4];  // [4,64,1]
    const float* Bias = (const float*)d_in[5];  // [1,256]
    const float* PW   = (const float*)d_in[6];  // [256,256]
    const float* PB   = (const float*)d_in[7];  // [256]
    float* out = (float*)d_out;                 // [8192,256] fp32

    char* ws = (char*)d_ws;
    u16*   suppT = (u16*)(ws);                                   // 4 MiB
    float* f1    = (float*)(ws + (4u << 20));                    // 128 KiB
    float* f2    = (float*)(ws + (4u << 20) + (128u << 10));     // 128 KiB
    float* f1mx  = (float*)(ws + (4u << 20) + (256u << 10));     // 64 B
    float* PWT   = (float*)(ws + (4u << 20) + (320u << 10));     // 256 KiB
    float* EAp   = (float*)(ws + (4u << 20) + (576u << 10));     // 128 KiB
    float* EBp   = (float*)(ws + (4u << 20) + (704u << 10));     // 128 KiB
    float* aden  = (float*)(ws + (4u << 20) + (832u << 10));     // 128 KiB
    u16*   gbits = (u16*)(ws + (8u << 20));                      // 16 MiB
    float* anum  = (float*)(ws + (24u << 20));                   // 8 MiB

    k_tr<<<16, 256, 0, stream>>>(PW, PWT);
    k_gemm<<<N_NODES / RPB, 256, 0, stream>>>(inp, W, U, V, Bias, PWT, PB, adj,
                                              suppT, f1, f2, out, gbits, anum, aden);
    k_prep<<<NHEAD, 256, 0, stream>>>(f1, f1mx, EAp, EBp);
    k_attn_mfma<<<(N_NODES / TI) * JSPLIT_G, 256, 0, stream>>>(
        gbits, suppT, EAp, EBp, f2, f1mx, anum, aden);
    k_fin<<<N_NODES / 4, 256, 0, stream>>>(anum, aden, out);
}

// Round 8
// 531.110 us; speedup vs baseline: 1.1197x; 1.1197x over previous
//
#include <hip/hip_runtime.h>
#include <hip/hip_bf16.h>

#define N_NODES 8192
#define IN_FEAT 256
#define OUT_F   64
#define NHEAD   4
#define HF      256     // NHEAD*OUT_F
#define NEG     0.2f

typedef unsigned short u16;
typedef unsigned long long u64;
typedef __attribute__((ext_vector_type(8))) short short8;   // 8 bf16 (4 VGPRs)
typedef __attribute__((ext_vector_type(4))) float f32x4;    // MFMA C/D

__device__ __forceinline__ u16 f2bf(float f) {
    union { unsigned int u; float f; } v; v.f = f;
    unsigned int r = v.u + 0x7FFFu + ((v.u >> 16) & 1u);  // RNE
    return (u16)(r >> 16);
}

// ---------------------------------------------------------------------------
// K0: PWT[k][c] = PW[c][k]  (256x256 fp32 transpose)
// ---------------------------------------------------------------------------
__global__ __launch_bounds__(256) void k_tr(const float* __restrict__ PW,
                                            float* __restrict__ PWT) {
    __shared__ float t[64][65];
    const int bx = (blockIdx.x & 3) * 64;   // k tile
    const int by = (blockIdx.x >> 2) * 64;  // c tile
    const int tx = threadIdx.x & 63;
    const int ty = threadIdx.x >> 6;
    #pragma unroll
    for (int r = ty; r < 64; r += 4)
        t[r][tx] = PW[(size_t)(by + r) * IN_FEAT + bx + tx];
    __syncthreads();
    #pragma unroll
    for (int r = ty; r < 64; r += 4)
        PWT[(size_t)(bx + r) * HF + by + tx] = t[tx][r];
}

// ---------------------------------------------------------------------------
// K1: per 4 rows: support = X@W written DIRECTLY in MFMA-B-fragment order
//     suppB[h][j/32][t][lane][8]  (lane=(q=j%32/8)*16 + (o%16), elem=j%8)
//     -> attn's B loads become lane-contiguous 1KB bursts.
//     Also: f1/f2 head dots, proj -> d_out, zero anum/aden, pack adjacency.
// ---------------------------------------------------------------------------
#define RPB 4
__global__ __launch_bounds__(256, 8) void k_gemm(
    const float* __restrict__ inp,   // [N, 256]
    const float* __restrict__ W,     // [256, 256] (k-major rows)
    const float* __restrict__ U,     // [H*64] flat
    const float* __restrict__ V,     // [H*64] flat
    const float* __restrict__ Bias,  // [256]
    const float* __restrict__ PWT,   // [256 k][256 c]
    const float* __restrict__ PB,    // [256]
    const float* __restrict__ adj,   // [N, N] fp32
    u16*   __restrict__ suppB,       // [H][256][4][64][8] bf16 fragments
    float* __restrict__ f1,          // [H][N]
    float* __restrict__ f2,          // [H][N]
    float* __restrict__ outp,        // [N][256]  proj + bias + proj_b
    u16*   __restrict__ gb,          // [N][1024] nibble flags
    float* __restrict__ anum,        // [N][256]  zeroed here
    float* __restrict__ aden)        // [H][N]    zeroed here
{
    __shared__ __align__(16) float in_lds[RPB][IN_FEAT];
    const int c  = threadIdx.x;            // output column 0..255
    const int n0 = blockIdx.x * RPB;

    #pragma unroll
    for (int r = 0; r < RPB; ++r)
        in_lds[r][c] = inp[(size_t)(n0 + r) * IN_FEAT + c];
    __syncthreads();

    float accs[RPB], accp[RPB];
    #pragma unroll
    for (int r = 0; r < RPB; ++r) { accs[r] = 0.f; accp[r] = 0.f; }

    const float* wc = W   + c;
    const float* pc = PWT + c;
    float w0 = wc[0 * HF], w1 = wc[1 * HF], w2 = wc[2 * HF], w3 = wc[3 * HF];
    float p0 = pc[0 * HF], p1 = pc[1 * HF], p2 = pc[2 * HF], p3 = pc[3 * HF];

    #pragma unroll 1
    for (int k = 0; k < IN_FEAT; k += 4) {
        const int kn = (k + 4) & 255;          // wrap: last prefetch discarded
        const float nw0 = wc[(kn + 0) * HF];
        const float nw1 = wc[(kn + 1) * HF];
        const float nw2 = wc[(kn + 2) * HF];
        const float nw3 = wc[(kn + 3) * HF];
        const float np0 = pc[(kn + 0) * HF];
        const float np1 = pc[(kn + 1) * HF];
        const float np2 = pc[(kn + 2) * HF];
        const float np3 = pc[(kn + 3) * HF];
        #pragma unroll
        for (int r = 0; r < RPB; ++r) {
            const float4 xv = *(const float4*)&in_lds[r][k];
            accs[r] = fmaf(xv.x, w0, accs[r]);
            accs[r] = fmaf(xv.y, w1, accs[r]);
            accs[r] = fmaf(xv.z, w2, accs[r]);
            accs[r] = fmaf(xv.w, w3, accs[r]);
            accp[r] = fmaf(xv.x, p0, accp[r]);
            accp[r] = fmaf(xv.y, p1, accp[r]);
            accp[r] = fmaf(xv.z, p2, accp[r]);
            accp[r] = fmaf(xv.w, p3, accp[r]);
        }
        w0 = nw0; w1 = nw1; w2 = nw2; w3 = nw3;
        p0 = np0; p1 = np1; p2 = np2; p3 = np3;
    }

    const int h = c >> 6, lane = c & 63;
    const float uv = U[c], vv = V[c];
    const float bb = Bias[c] + PB[c];

    // fragment-order support store: one 8B store (4 consecutive j of this col)
    {
        const int o   = c & 63;
        const int t   = o >> 4;
        const int cc  = o & 15;
        const int jbg = n0 >> 5;               // n0..n0+3 share the 32-block
        const int q   = (n0 & 31) >> 3;        //   and the 8-sub-block
        const int el  = n0 & 7;                // 0 or 4
        union { short s[4]; u64 q8; } sv;
        #pragma unroll
        for (int r = 0; r < RPB; ++r) sv.s[r] = (short)f2bf(accs[r]);
        const size_t word = ((size_t)(h * 256 + jbg) * 4 + t) * 64 + (q << 4) + cc;
        *(u64*)(suppB + word * 8 + el) = sv.q8;
    }

    #pragma unroll
    for (int r = 0; r < RPB; ++r) {
        float s1 = accs[r] * uv, s2 = accs[r] * vv;
        #pragma unroll
        for (int mm = 32; mm > 0; mm >>= 1) {
            s1 += __shfl_xor(s1, mm);
            s2 += __shfl_xor(s2, mm);
        }
        if (lane == 0) {
            f1[h * N_NODES + n0 + r] = s1;
            f2[h * N_NODES + n0 + r] = s2;
        }
        outp[(size_t)(n0 + r) * HF + c] = accp[r] + bb;
    }

    // ---- fused tail: zero attn accumulators ----
    #pragma unroll
    for (int r = 0; r < RPB; ++r)
        anum[(size_t)(n0 + r) * HF + c] = 0.f;
    if (c < 16)
        aden[(size_t)(c >> 2) * N_NODES + n0 + (c & 3)] = 0.f;

    // ---- fused tail: pack adjacency rows n0..n0+3 into nibble flags ----
    #pragma unroll
    for (int r = 0; r < RPB; ++r) {
        const float* ar = adj + (size_t)(n0 + r) * N_NODES;
        u16* gr = gb + (size_t)(n0 + r) * 1024;
        #pragma unroll
        for (int pass = 0; pass < 4; ++pass) {
            const int w = pass * 256 + c;
            const float4 a0 = *(const float4*)(ar + w * 8);
            const float4 a1 = *(const float4*)(ar + w * 8 + 4);
            gr[w] = (u16)(
                (unsigned)(a0.x != 0.f)        | ((unsigned)(a0.y != 0.f) << 1) |
                ((unsigned)(a0.z != 0.f) << 2) | ((unsigned)(a0.w != 0.f) << 3) |
                ((unsigned)(a1.x != 0.f) << 8) | ((unsigned)(a1.y != 0.f) << 9) |
                ((unsigned)(a1.z != 0.f) << 10)| ((unsigned)(a1.w != 0.f) << 11));
        }
    }
}

// ---------------------------------------------------------------------------
// K2: per-head f1 max + interleaved factored-exponential table:
//     EAB[h][2j] = exp(f1j - f1max), EAB[h][2j+1] = exp(0.2*(f1j - f1max))
// ---------------------------------------------------------------------------
__global__ __launch_bounds__(256) void k_prep(const float* __restrict__ f1,
                                              float* __restrict__ f1max,
                                              float* __restrict__ EAB) {
    __shared__ float red[256];
    const int h = blockIdx.x;
    float m = -1e30f;
    for (int j = threadIdx.x; j < N_NODES; j += 256)
        m = fmaxf(m, f1[h * N_NODES + j]);
    red[threadIdx.x] = m;
    __syncthreads();
    for (int s = 128; s > 0; s >>= 1) {
        if (threadIdx.x < s) red[threadIdx.x] = fmaxf(red[threadIdx.x], red[threadIdx.x + s]);
        __syncthreads();
    }
    const float fm = red[0];
    if (threadIdx.x == 0) f1max[h] = fm;
    for (int j = threadIdx.x; j < N_NODES; j += 256) {
        const float d = f1[h * N_NODES + j] - fm;
        EAB[(size_t)h * 2 * N_NODES + 2 * j]     = __expf(d);
        EAB[(size_t)h * 2 * N_NODES + 2 * j + 1] = __expf(NEG * d);
    }
}

// ---------------------------------------------------------------------------
// K3: MFMA attention, TI=64, grid 512 = 128 i-tiles x 4 j-windows, 4 waves =
//   4 heads. Per-step memory is now DENSE:
//     - 4 B loads from suppB fragments: lane L reads base+16L (1KB bursts)
//     - 4 EAB float4 broadcast loads (EA,EB interleaved)
//     - 4 flag ds_read_u16 from LDS (33KB, stride 520B -> <=2-way conflicts)
//   vs round 7's 12 scattered global loads (~160 cache-line requests/step).
//   Partials combine via float atomics into anum/aden (zeroed by k_gemm).
// ---------------------------------------------------------------------------
#define TI 64
#define NSUB 4
#define JSPLIT_G 4
#define JW (N_NODES / JSPLIT_G)     // 2048-j window per block
#define ABW 260                     // u16 row stride: 520B (8B-aligned)

__global__ __launch_bounds__(256, 2) void k_attn_mfma(
    const u16* __restrict__ gbits,   // [N][1024] nibble flags
    const u16* __restrict__ suppB,   // [H][256][4][64][8] bf16 fragments
    const float* __restrict__ EAB,   // [H][N][2] interleaved exp tables
    const float* __restrict__ f2,    // [H][N]
    const float* __restrict__ f1max, // [H]
    float* __restrict__ anum,        // [N][256] numerator accumulator
    float* __restrict__ aden)        // [H][N]   denominator accumulator
{
    __shared__ u16 abits[TI][ABW];   // 33.3 KB

    const int itile = blockIdx.x >> 2;       // 0..127
    const int jwin  = blockIdx.x & 3;        // j-window
    const int i0    = itile * TI;
    const int J0    = jwin * JW;
    const int wv    = threadIdx.x >> 6;      // wave = head
    const int lane  = threadIdx.x & 63;
    const int col   = lane & 15;             // m (A) / n (B) / col (C)
    const int quad  = lane >> 4;

    // ---- Phase 1: stage flag words for this window (wave wv: 16 rows) ----
    #pragma unroll
    for (int rr = 0; rr < 16; ++rr) {
        const int r = wv * 16 + rr;
        *(u64*)&abits[r][lane * 4] =
            *(const u64*)(gbits + (size_t)(i0 + r) * 1024 + (J0 >> 3) + lane * 4);
    }
    __syncthreads();

    // ---- Phase 2: dense flash j-loop, 4 i-subtiles ----
    const int h = wv;
    const float fm = f1max[h];
    float CA[NSUB], CB[NSUB], ls[NSUB];
    #pragma unroll
    for (int s = 0; s < NSUB; ++s) {
        const float f2i = f2[(size_t)h * N_NODES + i0 + s * 16 + col];
        const float g  = fm + f2i;
        const float mi = fmaxf(g, NEG * g);                 // leaky(g)
        CA[s] = __expf(g - mi);
        CB[s] = __expf(NEG * g - mi);
        ls[s] = 0.f;
    }

    const float* EABh = EAB + (size_t)h * 2 * N_NODES + 2 * J0;
    const u16*   sb   = suppB + (size_t)h * 524288           // h*256*2048
                      + (size_t)(J0 >> 5) * 2048 + lane * 8;

    f32x4 acc[NSUB][4];
    #pragma unroll
    for (int s = 0; s < NSUB; ++s)
        #pragma unroll
        for (int t = 0; t < 4; ++t)
            acc[s][t] = (f32x4){0.f, 0.f, 0.f, 0.f};

    const int qo = quad << 3;

    #pragma unroll 1
    for (int jb = 0; jb < JW; jb += 32) {
        const int jl = jb + qo;                             // lane's local j
        const u16* fp = sb + (size_t)(jb >> 5) * 2048;      // fragment base
        const short8 bv0 = *(const short8*)(fp);
        const short8 bv1 = *(const short8*)(fp + 512);
        const short8 bv2 = *(const short8*)(fp + 1024);
        const short8 bv3 = *(const short8*)(fp + 1536);
        const float4 ep0 = *(const float4*)(EABh + 2 * jl);
        const float4 ep1 = *(const float4*)(EABh + 2 * jl + 4);
        const float4 ep2 = *(const float4*)(EABh + 2 * jl + 8);
        const float4 ep3 = *(const float4*)(EABh + 2 * jl + 12);
        const int wo = (jb >> 3) + quad;                    // flag word offset
        u16 gw[NSUB];
        #pragma unroll
        for (int s = 0; s < NSUB; ++s) gw[s] = abits[col + s * 16][wo];

        const float4 ep[4] = {ep0, ep1, ep2, ep3};

        #pragma unroll
        for (int s = 0; s < NSUB; ++s) {
            union { short8 v; unsigned w[4]; } af;
            #pragma unroll
            for (int p = 0; p < 4; ++p) {
                const int je = 2 * p, jo = 2 * p + 1;
                const int she = (je & 3) + ((je >> 2) << 3);
                const int sho = (jo & 3) + ((jo >> 2) << 3);
                float xe = fmaxf(ep[p].x * CA[s], ep[p].y * CB[s]);
                float xo = fmaxf(ep[p].z * CA[s], ep[p].w * CB[s]);
                const unsigned me = 0u - ((unsigned)(gw[s] >> she) & 1u);
                const unsigned mo = 0u - ((unsigned)(gw[s] >> sho) & 1u);
                xe = __uint_as_float(__float_as_uint(xe) & me);
                xo = __uint_as_float(__float_as_uint(xo) & mo);
                ls[s] += xe;
                ls[s] += xo;
                asm("v_cvt_pk_bf16_f32 %0, %1, %2"
                    : "=v"(af.w[p]) : "v"(xe), "v"(xo));
            }
            acc[s][0] = __builtin_amdgcn_mfma_f32_16x16x32_bf16(af.v, bv0, acc[s][0], 0, 0, 0);
            acc[s][1] = __builtin_amdgcn_mfma_f32_16x16x32_bf16(af.v, bv1, acc[s][1], 0, 0, 0);
            acc[s][2] = __builtin_amdgcn_mfma_f32_16x16x32_bf16(af.v, bv2, acc[s][2], 0, 0, 0);
            acc[s][3] = __builtin_amdgcn_mfma_f32_16x16x32_bf16(af.v, bv3, acc[s][3], 0, 0, 0);
        }
    }

    // denominators: reduce over quads; then every lane holds sum for i=lane&15
    #pragma unroll
    for (int s = 0; s < NSUB; ++s) {
        ls[s] += __shfl_xor(ls[s], 16);
        ls[s] += __shfl_xor(ls[s], 32);
    }
    if (quad == 0) {
        #pragma unroll
        for (int s = 0; s < NSUB; ++s)
            unsafeAtomicAdd(aden + (size_t)h * N_NODES + i0 + s * 16 + col, ls[s]);
    }

    // numerators: C layout col=lane&15, row=quad*4+reg
    #pragma unroll
    for (int s = 0; s < NSUB; ++s) {
        #pragma unroll
        for (int reg = 0; reg < 4; ++reg) {
            const int irow = (quad << 2) + reg;
            float* ap = anum + (size_t)(i0 + s * 16 + irow) * HF + (h << 6) + col;
            #pragma unroll
            for (int t = 0; t < 4; ++t)
                unsafeAtomicAdd(ap + (t << 4), acc[s][t][reg]);
        }
    }
}

// ---------------------------------------------------------------------------
// K4: out += anum / aden   (denominator > 0 guaranteed by self-loops)
// ---------------------------------------------------------------------------
__global__ __launch_bounds__(256) void k_fin(const float* __restrict__ anum,
                                             const float* __restrict__ aden,
                                             float* __restrict__ out) {
    const int c = threadIdx.x;
    const int h = c >> 6;
    #pragma unroll
    for (int rr = 0; rr < 4; ++rr) {
        const int n = blockIdx.x * 4 + rr;
        out[(size_t)n * HF + c] += anum[(size_t)n * HF + c]
                                 / aden[(size_t)h * N_NODES + n];
    }
}

// ---------------------------------------------------------------------------
extern "C" void kernel_launch(void* const* d_in, const int* in_sizes, int n_in,
                              void* d_out, int out_size, void* d_ws, size_t ws_size,
                              hipStream_t stream) {
    const float* inp  = (const float*)d_in[0];  // [8192,256]
    const float* adj  = (const float*)d_in[1];  // [8192,8192]
    const float* W    = (const float*)d_in[2];  // [256,256]
    const float* U    = (const float*)d_in[3];  // [4,64,1]
    const float* V    = (const float*)d_in[4];  // [4,64,1]
    const float* Bias = (const float*)d_in[5];  // [1,256]
    const float* PW   = (const float*)d_in[6];  // [256,256]
    const float* PB   = (const float*)d_in[7];  // [256]
    float* out = (float*)d_out;                 // [8192,256] fp32

    char* ws = (char*)d_ws;
    u16*   suppB = (u16*)(ws);                                   // 4 MiB
    float* f1    = (float*)(ws + (4u << 20));                    // 128 KiB
    float* f2    = (float*)(ws + (4u << 20) + (128u << 10));     // 128 KiB
    float* f1mx  = (float*)(ws + (4u << 20) + (256u << 10));     // 64 B
    float* PWT   = (float*)(ws + (4u << 20) + (320u << 10));     // 256 KiB
    float* EAB   = (float*)(ws + (4u << 20) + (576u << 10));     // 256 KiB
    float* aden  = (float*)(ws + (4u << 20) + (832u << 10));     // 128 KiB
    u16*   gbits = (u16*)(ws + (8u << 20));                      // 16 MiB
    float* anum  = (float*)(ws + (24u << 20));                   // 8 MiB

    k_tr<<<16, 256, 0, stream>>>(PW, PWT);
    k_gemm<<<N_NODES / RPB, 256, 0, stream>>>(inp, W, U, V, Bias, PWT, PB, adj,
                                              suppB, f1, f2, out, gbits, anum, aden);
    k_prep<<<NHEAD, 256, 0, stream>>>(f1, f1mx, EAB);
    k_attn_mfma<<<(N_NODES / TI) * JSPLIT_G, 256, 0, stream>>>(
        gbits, suppB, EAB, f2, f1mx, anum, aden);
    k_fin<<<N_NODES / 4, 256, 0, stream>>>(anum, aden, out);
}

// Round 9
// 517.347 us; speedup vs baseline: 1.1494x; 1.0266x over previous
//
#include <hip/hip_runtime.h>
#include <hip/hip_bf16.h>

#define N_NODES 8192
#define IN_FEAT 256
#define OUT_F   64
#define NHEAD   4
#define HF      256     // NHEAD*OUT_F
#define NEG     0.2f

typedef unsigned short u16;
typedef unsigned char  u8;
typedef unsigned long long u64;
typedef _Float16 h2    __attribute__((ext_vector_type(2)));
typedef _Float16 half8 __attribute__((ext_vector_type(8)));
typedef __attribute__((ext_vector_type(4))) float f32x4;    // MFMA C/D

// ---------------------------------------------------------------------------
// K0: PWT[k][c] = PW[c][k]  (256x256 fp32 transpose)
// ---------------------------------------------------------------------------
__global__ __launch_bounds__(256) void k_tr(const float* __restrict__ PW,
                                            float* __restrict__ PWT) {
    __shared__ float t[64][65];
    const int bx = (blockIdx.x & 3) * 64;   // k tile
    const int by = (blockIdx.x >> 2) * 64;  // c tile
    const int tx = threadIdx.x & 63;
    const int ty = threadIdx.x >> 6;
    #pragma unroll
    for (int r = ty; r < 64; r += 4)
        t[r][tx] = PW[(size_t)(by + r) * IN_FEAT + bx + tx];
    __syncthreads();
    #pragma unroll
    for (int r = ty; r < 64; r += 4)
        PWT[(size_t)(bx + r) * HF + by + tx] = t[tx][r];
}

// ---------------------------------------------------------------------------
// K1: per 4 rows: support = X@W -> suppB (fp16, MFMA-B-fragment order),
//     f1/f2 head dots, proj = X@PWT + proj_b + bias -> d_out,
//     zero anum/aden, pack adjacency into straight-bit bytes (u32/thread).
// ---------------------------------------------------------------------------
#define RPB 4
__global__ __launch_bounds__(256, 8) void k_gemm(
    const float* __restrict__ inp,   // [N, 256]
    const float* __restrict__ W,     // [256, 256] (k-major rows)
    const float* __restrict__ U,     // [H*64] flat
    const float* __restrict__ V,     // [H*64] flat
    const float* __restrict__ Bias,  // [256]
    const float* __restrict__ PWT,   // [256 k][256 c]
    const float* __restrict__ PB,    // [256]
    const float* __restrict__ adj,   // [N, N] fp32
    _Float16* __restrict__ suppB,    // [H][256][4][64][8] fp16 fragments
    float* __restrict__ f1,          // [H][N]
    float* __restrict__ f2,          // [H][N]
    float* __restrict__ outp,        // [N][256]  proj + bias + proj_b
    unsigned* __restrict__ gb32,     // [N][256] straight-bit flag words
    float* __restrict__ anum,        // [N][256]  zeroed here
    float* __restrict__ aden)        // [H][N]    zeroed here
{
    __shared__ __align__(16) float in_lds[RPB][IN_FEAT];
    const int c  = threadIdx.x;            // output column 0..255
    const int n0 = blockIdx.x * RPB;

    #pragma unroll
    for (int r = 0; r < RPB; ++r)
        in_lds[r][c] = inp[(size_t)(n0 + r) * IN_FEAT + c];
    __syncthreads();

    float accs[RPB], accp[RPB];
    #pragma unroll
    for (int r = 0; r < RPB; ++r) { accs[r] = 0.f; accp[r] = 0.f; }

    const float* wc = W   + c;
    const float* pc = PWT + c;
    float w0 = wc[0 * HF], w1 = wc[1 * HF], w2 = wc[2 * HF], w3 = wc[3 * HF];
    float p0 = pc[0 * HF], p1 = pc[1 * HF], p2 = pc[2 * HF], p3 = pc[3 * HF];

    #pragma unroll 1
    for (int k = 0; k < IN_FEAT; k += 4) {
        const int kn = (k + 4) & 255;          // wrap: last prefetch discarded
        const float nw0 = wc[(kn + 0) * HF];
        const float nw1 = wc[(kn + 1) * HF];
        const float nw2 = wc[(kn + 2) * HF];
        const float nw3 = wc[(kn + 3) * HF];
        const float np0 = pc[(kn + 0) * HF];
        const float np1 = pc[(kn + 1) * HF];
        const float np2 = pc[(kn + 2) * HF];
        const float np3 = pc[(kn + 3) * HF];
        #pragma unroll
        for (int r = 0; r < RPB; ++r) {
            const float4 xv = *(const float4*)&in_lds[r][k];
            accs[r] = fmaf(xv.x, w0, accs[r]);
            accs[r] = fmaf(xv.y, w1, accs[r]);
            accs[r] = fmaf(xv.z, w2, accs[r]);
            accs[r] = fmaf(xv.w, w3, accs[r]);
            accp[r] = fmaf(xv.x, p0, accp[r]);
            accp[r] = fmaf(xv.y, p1, accp[r]);
            accp[r] = fmaf(xv.z, p2, accp[r]);
            accp[r] = fmaf(xv.w, p3, accp[r]);
        }
        w0 = nw0; w1 = nw1; w2 = nw2; w3 = nw3;
        p0 = np0; p1 = np1; p2 = np2; p3 = np3;
    }

    const int h = c >> 6, lane = c & 63;
    const float uv = U[c], vv = V[c];
    const float bb = Bias[c] + PB[c];

    // fragment-order support store (fp16): one 8B store
    {
        const int o   = c & 63;
        const int t   = o >> 4;
        const int cc  = o & 15;
        const int jbg = n0 >> 5;
        const int q   = (n0 & 31) >> 3;
        const int el  = n0 & 7;                // 0 or 4
        union { _Float16 hh[4]; u64 q8; } sv;
        #pragma unroll
        for (int r = 0; r < RPB; ++r) sv.hh[r] = (_Float16)accs[r];
        const size_t word = ((size_t)(h * 256 + jbg) * 4 + t) * 64 + (q << 4) + cc;
        *(u64*)(suppB + word * 8 + el) = sv.q8;
    }

    #pragma unroll
    for (int r = 0; r < RPB; ++r) {
        float s1 = accs[r] * uv, s2 = accs[r] * vv;
        #pragma unroll
        for (int mm = 32; mm > 0; mm >>= 1) {
            s1 += __shfl_xor(s1, mm);
            s2 += __shfl_xor(s2, mm);
        }
        if (lane == 0) {
            f1[h * N_NODES + n0 + r] = s1;
            f2[h * N_NODES + n0 + r] = s2;
        }
        outp[(size_t)(n0 + r) * HF + c] = accp[r] + bb;
    }

    // ---- fused tail: zero attn accumulators ----
    #pragma unroll
    for (int r = 0; r < RPB; ++r)
        anum[(size_t)(n0 + r) * HF + c] = 0.f;
    if (c < 16)
        aden[(size_t)(c >> 2) * N_NODES + n0 + (c & 3)] = 0.f;

    // ---- fused tail: pack adjacency rows, straight bit order ----
    // byte b of row covers j=8b..8b+7, bit k = (adj[8b+k]!=0). u32/thread/row.
    #pragma unroll
    for (int r = 0; r < RPB; ++r) {
        const float* ar = adj + (size_t)(n0 + r) * N_NODES;
        unsigned wrd = 0;
        #pragma unroll
        for (int p = 0; p < 4; ++p) {
            const int j = c * 32 + p * 8;
            const float4 a0 = *(const float4*)(ar + j);
            const float4 a1 = *(const float4*)(ar + j + 4);
            const unsigned b =
                (unsigned)(a0.x != 0.f)        | ((unsigned)(a0.y != 0.f) << 1) |
                ((unsigned)(a0.z != 0.f) << 2) | ((unsigned)(a0.w != 0.f) << 3) |
                ((unsigned)(a1.x != 0.f) << 4) | ((unsigned)(a1.y != 0.f) << 5) |
                ((unsigned)(a1.z != 0.f) << 6) | ((unsigned)(a1.w != 0.f) << 7);
            wrd |= b << (8 * p);
        }
        gb32[(size_t)(n0 + r) * 256 + c] = wrd;
    }
}

// ---------------------------------------------------------------------------
// K2: per-head f1 max + fp16 factored-exponential planes:
//     EA16[h][j] = (fp16) exp(f1j - f1max), EB16[h][j] = (fp16) exp(0.2*d)
// ---------------------------------------------------------------------------
__global__ __launch_bounds__(256) void k_prep(const float* __restrict__ f1,
                                              float* __restrict__ f1max,
                                              _Float16* __restrict__ EA16,
                                              _Float16* __restrict__ EB16) {
    __shared__ float red[256];
    const int h = blockIdx.x;
    float m = -1e30f;
    for (int j = threadIdx.x; j < N_NODES; j += 256)
        m = fmaxf(m, f1[h * N_NODES + j]);
    red[threadIdx.x] = m;
    __syncthreads();
    for (int s = 128; s > 0; s >>= 1) {
        if (threadIdx.x < s) red[threadIdx.x] = fmaxf(red[threadIdx.x], red[threadIdx.x + s]);
        __syncthreads();
    }
    const float fm = red[0];
    if (threadIdx.x == 0) f1max[h] = fm;
    for (int j = threadIdx.x; j < N_NODES; j += 256) {
        const float d = f1[h * N_NODES + j] - fm;
        EA16[(size_t)h * N_NODES + j] = (_Float16)__expf(d);
        EB16[(size_t)h * N_NODES + j] = (_Float16)__expf(NEG * d);
    }
}

// ---------------------------------------------------------------------------
// K3: MFMA attention, fp16 path. TI=64, grid 512 = 128 i-tiles x 4 j-windows,
//   4 waves = 4 heads. Phase 1 stages EA/EB windows (32 KB) + flag bytes
//   (16.6 KB) in LDS -> the VALU phase depends only on LDS; the only global
//   loads per step are 4 dense fp16 B-fragments consumed by MFMA at the end.
//   P-construction per j-pair: pk_mul x2 + pk_max (result IS the packed
//   A-fragment half-word pair), sign-extended bit masks, fdot2 denominator.
// ---------------------------------------------------------------------------
#define TI 64
#define NSUB 4
#define JSPLIT_G 4
#define JW (N_NODES / JSPLIT_G)     // 2048-j window per block

__global__ __launch_bounds__(256, 3) void k_attn_mfma(
    const unsigned* __restrict__ gb32,  // [N][256] straight-bit flags
    const _Float16* __restrict__ suppB, // [H][256][4][64][8] fp16 fragments
    const _Float16* __restrict__ EA16,  // [H][N] fp16 exp(f1 - f1max)
    const _Float16* __restrict__ EB16,  // [H][N] fp16 exp(0.2*(f1 - f1max))
    const float* __restrict__ f2,       // [H][N]
    const float* __restrict__ f1max,    // [H]
    float* __restrict__ anum,           // [N][256] numerator accumulator
    float* __restrict__ aden)           // [H][N]   denominator accumulator
{
    __shared__ __align__(16) _Float16 ea_lds[NHEAD][JW];   // 16 KB
    __shared__ __align__(16) _Float16 eb_lds[NHEAD][JW];   // 16 KB
    __shared__ __align__(4)  u8 abyte[TI][260];            // 16.6 KB padded

    const int itile = blockIdx.x >> 2;       // 0..127
    const int jwin  = blockIdx.x & 3;        // j-window
    const int i0    = itile * TI;
    const int J0    = jwin * JW;
    const int wv    = threadIdx.x >> 6;      // wave = head
    const int lane  = threadIdx.x & 63;
    const int col   = lane & 15;             // m (A) / n (B) / col (C)
    const int quad  = lane >> 4;

    // ---- Phase 1a: stage fp16 exp planes for this head's window ----
    {
        const _Float16* gea = EA16 + (size_t)wv * N_NODES + J0;
        const _Float16* geb = EB16 + (size_t)wv * N_NODES + J0;
        #pragma unroll
        for (int it = 0; it < 4; ++it) {
            const int off = it * 512 + lane * 8;
            *(float4*)&ea_lds[wv][off] = *(const float4*)(gea + off);
            *(float4*)&eb_lds[wv][off] = *(const float4*)(geb + off);
        }
    }
    // ---- Phase 1b: stage flag bytes (wave wv: 16 rows x 256 B) ----
    #pragma unroll
    for (int rr = 0; rr < 16; ++rr) {
        const int r = (wv << 4) + rr;
        *(unsigned*)&abyte[r][lane * 4] =
            gb32[(size_t)(i0 + r) * 256 + (J0 >> 5) + lane];
    }
    __syncthreads();

    // ---- Phase 2: fp16 flash j-loop, 4 i-subtiles ----
    const int h = wv;
    const float fm = f1max[h];
    h2 caH[NSUB], cbH[NSUB];
    float ls[NSUB];
    #pragma unroll
    for (int s = 0; s < NSUB; ++s) {
        const float f2i = f2[(size_t)h * N_NODES + i0 + s * 16 + col];
        const float g  = fm + f2i;
        const float mi = fmaxf(g, NEG * g);                 // leaky(g)
        const _Float16 ca = (_Float16)__expf(g - mi);
        const _Float16 cb = (_Float16)__expf(NEG * g - mi);
        caH[s][0] = ca; caH[s][1] = ca;
        cbH[s][0] = cb; cbH[s][1] = cb;
        ls[s] = 0.f;
    }
    const h2 ones = {(_Float16)1.0f, (_Float16)1.0f};

    const _Float16* sb = suppB + (size_t)h * 524288          // h*256*2048
                       + (size_t)(J0 >> 5) * 2048 + lane * 8;

    f32x4 acc[NSUB][4];
    #pragma unroll
    for (int s = 0; s < NSUB; ++s)
        #pragma unroll
        for (int t = 0; t < 4; ++t)
            acc[s][t] = (f32x4){0.f, 0.f, 0.f, 0.f};

    const int qo = quad << 3;

    #pragma unroll 2
    for (int jb = 0; jb < JW; jb += 32) {
        const int jl = jb + qo;                             // lane's local j
        const _Float16* fp = sb + (size_t)(jb >> 5) * 2048; // fragment base
        const half8 bv0 = *(const half8*)(fp);
        const half8 bv1 = *(const half8*)(fp + 512);
        const half8 bv2 = *(const half8*)(fp + 1024);
        const half8 bv3 = *(const half8*)(fp + 1536);

        union { half8 v; h2 pr[4]; } ea, eb;
        ea.v = *(const half8*)&ea_lds[h][jl];
        eb.v = *(const half8*)&eb_lds[h][jl];
        const int wo = (jb >> 3) + quad;                    // flag byte offset

        #pragma unroll
        for (int s = 0; s < NSUB; ++s) {
            const unsigned gw = abyte[col + s * 16][wo];
            union { half8 v; unsigned w[4]; h2 pr[4]; } af;
            #pragma unroll
            for (int p = 0; p < 4; ++p) {
                const h2 pa = ea.pr[p] * caH[s];            // v_pk_mul_f16
                const h2 pb = eb.pr[p] * cbH[s];
                const h2 x  = __builtin_elementwise_max(pa, pb); // v_pk_max
                // sign-extended per-element masks from straight bits 2p,2p+1
                const unsigned mlo = (unsigned)((int)(gw << (31 - 2 * p)) >> 31) & 0x0000FFFFu;
                const unsigned mhi = (unsigned)((int)(gw << (30 - 2 * p)) >> 31) & 0xFFFF0000u;
                union { h2 hh; unsigned u; } xu;
                xu.hh = x;
                xu.u &= (mlo | mhi);
                af.w[p] = xu.u;
                ls[s] = __builtin_amdgcn_fdot2(xu.hh, ones, ls[s], false);
            }
            acc[s][0] = __builtin_amdgcn_mfma_f32_16x16x32_f16(af.v, bv0, acc[s][0], 0, 0, 0);
            acc[s][1] = __builtin_amdgcn_mfma_f32_16x16x32_f16(af.v, bv1, acc[s][1], 0, 0, 0);
            acc[s][2] = __builtin_amdgcn_mfma_f32_16x16x32_f16(af.v, bv2, acc[s][2], 0, 0, 0);
            acc[s][3] = __builtin_amdgcn_mfma_f32_16x16x32_f16(af.v, bv3, acc[s][3], 0, 0, 0);
        }
    }

    // denominators: reduce over quads; lane L holds sum for i = L&15
    #pragma unroll
    for (int s = 0; s < NSUB; ++s) {
        ls[s] += __shfl_xor(ls[s], 16);
        ls[s] += __shfl_xor(ls[s], 32);
    }
    if (quad == 0) {
        #pragma unroll
        for (int s = 0; s < NSUB; ++s)
            unsafeAtomicAdd(aden + (size_t)h * N_NODES + i0 + s * 16 + col, ls[s]);
    }

    // numerators: C layout col=lane&15, row=quad*4+reg
    #pragma unroll
    for (int s = 0; s < NSUB; ++s) {
        #pragma unroll
        for (int reg = 0; reg < 4; ++reg) {
            const int irow = (quad << 2) + reg;
            float* ap = anum + (size_t)(i0 + s * 16 + irow) * HF + (h << 6) + col;
            #pragma unroll
            for (int t = 0; t < 4; ++t)
                unsafeAtomicAdd(ap + (t << 4), acc[s][t][reg]);
        }
    }
}

// ---------------------------------------------------------------------------
// K4: out += anum / aden   (denominator > 0 guaranteed by self-loops)
// ---------------------------------------------------------------------------
__global__ __launch_bounds__(256) void k_fin(const float* __restrict__ anum,
                                             const float* __restrict__ aden,
                                             float* __restrict__ out) {
    const int c = threadIdx.x;
    const int h = c >> 6;
    #pragma unroll
    for (int rr = 0; rr < 4; ++rr) {
        const int n = blockIdx.x * 4 + rr;
        out[(size_t)n * HF + c] += anum[(size_t)n * HF + c]
                                 / aden[(size_t)h * N_NODES + n];
    }
}

// ---------------------------------------------------------------------------
extern "C" void kernel_launch(void* const* d_in, const int* in_sizes, int n_in,
                              void* d_out, int out_size, void* d_ws, size_t ws_size,
                              hipStream_t stream) {
    const float* inp  = (const float*)d_in[0];  // [8192,256]
    const float* adj  = (const float*)d_in[1];  // [8192,8192]
    const float* W    = (const float*)d_in[2];  // [256,256]
    const float* U    = (const float*)d_in[3];  // [4,64,1]
    const float* V    = (const float*)d_in[4];  // [4,64,1]
    const float* Bias = (const float*)d_in[5];  // [1,256]
    const float* PW   = (const float*)d_in[6];  // [256,256]
    const float* PB   = (const float*)d_in[7];  // [256]
    float* out = (float*)d_out;                 // [8192,256] fp32

    char* ws = (char*)d_ws;
    _Float16* suppB = (_Float16*)(ws);                           // 4 MiB
    float* f1    = (float*)(ws + (4u << 20));                    // 128 KiB
    float* f2    = (float*)(ws + (4u << 20) + (128u << 10));     // 128 KiB
    float* f1mx  = (float*)(ws + (4u << 20) + (256u << 10));     // 64 B
    float* PWT   = (float*)(ws + (4u << 20) + (320u << 10));     // 256 KiB
    _Float16* EA16 = (_Float16*)(ws + (4u << 20) + (576u << 10));// 64 KiB
    _Float16* EB16 = (_Float16*)(ws + (4u << 20) + (704u << 10));// 64 KiB
    float* aden  = (float*)(ws + (4u << 20) + (832u << 10));     // 128 KiB
    unsigned* gb32 = (unsigned*)(ws + (8u << 20));               // 8 MiB
    float* anum  = (float*)(ws + (24u << 20));                   // 8 MiB

    k_tr<<<16, 256, 0, stream>>>(PW, PWT);
    k_gemm<<<N_NODES / RPB, 256, 0, stream>>>(inp, W, U, V, Bias, PWT, PB, adj,
                                              suppB, f1, f2, out, gb32, anum, aden);
    k_prep<<<NHEAD, 256, 0, stream>>>(f1, f1mx, EA16, EB16);
    k_attn_mfma<<<(N_NODES / TI) * JSPLIT_G, 256, 0, stream>>>(
        gb32, suppB, EA16, EB16, f2, f1mx, anum, aden);
    k_fin<<<N_NODES / 4, 256, 0, stream>>>(anum, aden, out);
}

// Round 10
// 487.822 us; speedup vs baseline: 1.2190x; 1.0605x over previous
//
#include <hip/hip_runtime.h>
#include <hip/hip_bf16.h>

#define N_NODES 8192
#define IN_FEAT 256
#define OUT_F   64
#define NHEAD   4
#define HF      256     // NHEAD*OUT_F
#define NEG     0.2f

typedef unsigned short u16;
typedef unsigned char  u8;
typedef unsigned int   u32;
typedef unsigned long long u64;
typedef _Float16 h2    __attribute__((ext_vector_type(2)));
typedef _Float16 half8 __attribute__((ext_vector_type(8)));
typedef __attribute__((ext_vector_type(4))) float f32x4;    // MFMA C/D

// ---------------------------------------------------------------------------
// K_x16: X fp32 -> fp16, and zero anum/aden (attn accumulators).
// ---------------------------------------------------------------------------
__global__ __launch_bounds__(256) void k_x16(const float* __restrict__ inp,
                                             _Float16* __restrict__ X16,
                                             float* __restrict__ anum,
                                             float* __restrict__ aden) {
    const int i = blockIdx.x * 256 + threadIdx.x;   // 0 .. 524287
    const float4 v = ((const float4*)inp)[i];
    union { _Float16 hh[4]; u64 q; } cv;
    cv.hh[0] = (_Float16)v.x; cv.hh[1] = (_Float16)v.y;
    cv.hh[2] = (_Float16)v.z; cv.hh[3] = (_Float16)v.w;
    ((u64*)X16)[i] = cv.q;
    ((float4*)anum)[i] = (float4){0.f, 0.f, 0.f, 0.f};
    if (i < 8192) ((float4*)aden)[i] = (float4){0.f, 0.f, 0.f, 0.f};
}

// ---------------------------------------------------------------------------
// K_wpack: build fp16 MFMA-B fragments for the 256x512 weight block
//   [W | PW^T]:  W16B[ks][T][lane=q*16+cc][e]  with k = ks*32+q*8+e,
//   n = T*16+cc.  n<256 -> W[k][n];  n>=256 -> PW[n-256][k]  (transpose read).
// ---------------------------------------------------------------------------
__global__ __launch_bounds__(256) void k_wpack(const float* __restrict__ W,
                                               const float* __restrict__ PW,
                                               _Float16* __restrict__ W16B) {
    const int w = blockIdx.x * 256 + threadIdx.x;   // word 0..16383
    const int ks = w >> 11;            // k-step 0..7
    const int T  = (w >> 6) & 31;      // n-tile 0..31
    const int lane = w & 63;
    const int q  = lane >> 4, cc = lane & 15;
    const int n  = T * 16 + cc;
    const int k0 = ks * 32 + q * 8;
    union { _Float16 hh[8]; half8 v; } o;
    #pragma unroll
    for (int e = 0; e < 8; ++e) {
        const int k = k0 + e;
        const float s = (n < 256) ? W[k * 256 + n] : PW[(size_t)(n - 256) * 256 + k];
        o.hh[e] = (_Float16)s;
    }
    *(half8*)(W16B + (size_t)w * 8) = o.v;
}

// ---------------------------------------------------------------------------
// K_bits: adjacency -> straight-order flag bits via wave ballot.
//   Lane l tests ONE element; __ballot gives 64 flag bits (bit l <-> j=jb+l)
//   in a single v_cmp. One wave per row, 32 iters of 256 j.
// ---------------------------------------------------------------------------
__global__ __launch_bounds__(256) void k_bits(const float* __restrict__ adj,
                                              u64* __restrict__ gb64) {  // [N][128]
    const int row  = blockIdx.x * 4 + (threadIdx.x >> 6);
    const int lane = threadIdx.x & 63;
    const float* ar = adj + (size_t)row * N_NODES;
    u64* gr = gb64 + (size_t)row * 128;
    #pragma unroll 1
    for (int it = 0; it < 32; ++it) {
        const int jb = it * 256;
        const float a0 = ar[jb + lane];
        const float a1 = ar[jb + 64 + lane];
        const float a2 = ar[jb + 128 + lane];
        const float a3 = ar[jb + 192 + lane];
        const u64 b0 = __ballot(a0 != 0.f);
        const u64 b1 = __ballot(a1 != 0.f);
        const u64 b2 = __ballot(a2 != 0.f);
        const u64 b3 = __ballot(a3 != 0.f);
        if (lane == 0) {
            gr[it * 4 + 0] = b0; gr[it * 4 + 1] = b1;
            gr[it * 4 + 2] = b2; gr[it * 4 + 3] = b3;
        }
    }
}

// ---------------------------------------------------------------------------
// K_gemm (MFMA): block = 16 rows x 512 cols ([supp | proj]), 4 waves, each
//   wave 16x128 (8 n-tiles) over K=256 (8 k-steps): 64 MFMAs/wave.
//   B-frags: lane-contiguous 16B bursts from L2-resident W16B.
//   Waves 0-1 (supp cols): store suppB in attn's fragment layout + f1/f2
//   via in-wave shfl reduce (each (h,row) owned by exactly one wave).
//   Waves 2-3 (proj cols): out = acc + Bias + PB.
// ---------------------------------------------------------------------------
#define GROWS 16
__global__ __launch_bounds__(256) void k_gemm(
    const _Float16* __restrict__ X16,   // [N][256] fp16
    const _Float16* __restrict__ W16B,  // [8][32][64][8] fp16 fragments
    const float* __restrict__ U,        // [256]
    const float* __restrict__ V,        // [256]
    const float* __restrict__ Bias,     // [256]
    const float* __restrict__ PB,       // [256]
    _Float16* __restrict__ suppB,       // [H][256][4][64][8] fp16 fragments
    float* __restrict__ f1,             // [H][N]
    float* __restrict__ f2,             // [H][N]
    float* __restrict__ outp)           // [N][256] proj + bias + proj_b
{
    __shared__ __align__(16) _Float16 xl[GROWS][264];   // 528B rows, 16B-aligned
    const int n0  = blockIdx.x * GROWS;
    const int tid = threadIdx.x;
    const int wv  = tid >> 6, lane = tid & 63;
    const int col = lane & 15, quad = lane >> 4;

    // stage 16 rows x 256 fp16 (coalesced 16B per thread x2)
    {
        const int r = tid >> 4, seg = tid & 15;
        const half8* src = (const half8*)(X16 + (size_t)(n0 + r) * 256 + seg * 16);
        *(half8*)&xl[r][seg * 16]     = src[0];
        *(half8*)&xl[r][seg * 16 + 8] = src[1];
    }
    __syncthreads();

    f32x4 acc[8];
    #pragma unroll
    for (int t = 0; t < 8; ++t) acc[t] = (f32x4){0.f, 0.f, 0.f, 0.f};

    const int qo = quad * 8;
    #pragma unroll
    for (int ks = 0; ks < 8; ++ks) {
        const half8 af = *(const half8*)&xl[col][ks * 32 + qo];
        const _Float16* bb = W16B + ((size_t)(ks * 32 + wv * 8) * 64 + lane) * 8;
        #pragma unroll
        for (int t = 0; t < 8; ++t) {
            const half8 bw = *(const half8*)(bb + (size_t)t * 512);
            acc[t] = __builtin_amdgcn_mfma_f32_16x16x32_f16(af, bw, acc[t], 0, 0, 0);
        }
    }

    if (wv < 2) {
        // ---- supp columns: emit attn fragment layout ----
        const int jbg = n0 >> 5;
        const int nlo = n0 & 31;
        #pragma unroll
        for (int t = 0; t < 8; ++t) {
            const int cg = wv * 128 + t * 16 + col;   // 0..255
            const int h  = cg >> 6;
            const int tp = (cg >> 4) & 3;
            #pragma unroll
            for (int reg = 0; reg < 4; ++reg) {
                const int irow = quad * 4 + reg;
                const int j31  = nlo + irow;
                const size_t word = ((size_t)(h * 256 + jbg) * 4 + tp) * 64
                                  + ((j31 >> 3) << 4) + col;
                suppB[word * 8 + (j31 & 7)] = (_Float16)acc[t][reg];
            }
        }
        // ---- f1/f2 head dots (heads wv*2, wv*2+1) ----
        float s1a[4] = {0,0,0,0}, s2a[4] = {0,0,0,0};
        float s1b[4] = {0,0,0,0}, s2b[4] = {0,0,0,0};
        #pragma unroll
        for (int t = 0; t < 8; ++t) {
            const int cg = wv * 128 + t * 16 + col;
            const float uu = U[cg], vv = V[cg];
            #pragma unroll
            for (int reg = 0; reg < 4; ++reg) {
                if (t < 4) { s1a[reg] += acc[t][reg] * uu; s2a[reg] += acc[t][reg] * vv; }
                else       { s1b[reg] += acc[t][reg] * uu; s2b[reg] += acc[t][reg] * vv; }
            }
        }
        #pragma unroll
        for (int m = 1; m < 16; m <<= 1) {
            #pragma unroll
            for (int reg = 0; reg < 4; ++reg) {
                s1a[reg] += __shfl_xor(s1a[reg], m);
                s2a[reg] += __shfl_xor(s2a[reg], m);
                s1b[reg] += __shfl_xor(s1b[reg], m);
                s2b[reg] += __shfl_xor(s2b[reg], m);
            }
        }
        if (col == 0) {
            const int hA = wv * 2, hB = wv * 2 + 1;
            #pragma unroll
            for (int reg = 0; reg < 4; ++reg) {
                const int n = n0 + quad * 4 + reg;
                f1[hA * N_NODES + n] = s1a[reg];
                f2[hA * N_NODES + n] = s2a[reg];
                f1[hB * N_NODES + n] = s1b[reg];
                f2[hB * N_NODES + n] = s2b[reg];
            }
        }
    } else {
        // ---- proj columns ----
        #pragma unroll
        for (int t = 0; t < 8; ++t) {
            const int cg = (wv - 2) * 128 + t * 16 + col;
            const float bb2 = Bias[cg] + PB[cg];
            #pragma unroll
            for (int reg = 0; reg < 4; ++reg) {
                const int irow = quad * 4 + reg;
                outp[(size_t)(n0 + irow) * HF + cg] = acc[t][reg] + bb2;
            }
        }
    }
}

// ---------------------------------------------------------------------------
// K2: per-head f1 max + fp16 factored-exponential planes.
// ---------------------------------------------------------------------------
__global__ __launch_bounds__(256) void k_prep(const float* __restrict__ f1,
                                              float* __restrict__ f1max,
                                              _Float16* __restrict__ EA16,
                                              _Float16* __restrict__ EB16) {
    __shared__ float red[256];
    const int h = blockIdx.x;
    float m = -1e30f;
    for (int j = threadIdx.x; j < N_NODES; j += 256)
        m = fmaxf(m, f1[h * N_NODES + j]);
    red[threadIdx.x] = m;
    __syncthreads();
    for (int s = 128; s > 0; s >>= 1) {
        if (threadIdx.x < s) red[threadIdx.x] = fmaxf(red[threadIdx.x], red[threadIdx.x + s]);
        __syncthreads();
    }
    const float fm = red[0];
    if (threadIdx.x == 0) f1max[h] = fm;
    for (int j = threadIdx.x; j < N_NODES; j += 256) {
        const float d = f1[h * N_NODES + j] - fm;
        EA16[(size_t)h * N_NODES + j] = (_Float16)__expf(d);
        EB16[(size_t)h * N_NODES + j] = (_Float16)__expf(NEG * d);
    }
}

// ---------------------------------------------------------------------------
// K3: MFMA attention (unchanged from round 9 fp16 path).
// ---------------------------------------------------------------------------
#define TI 64
#define NSUB 4
#define JSPLIT_G 4
#define JW (N_NODES / JSPLIT_G)     // 2048-j window per block

__global__ __launch_bounds__(256, 3) void k_attn_mfma(
    const unsigned* __restrict__ gb32,  // [N][256] straight-bit flags
    const _Float16* __restrict__ suppB, // [H][256][4][64][8] fp16 fragments
    const _Float16* __restrict__ EA16,  // [H][N] fp16 exp(f1 - f1max)
    const _Float16* __restrict__ EB16,  // [H][N] fp16 exp(0.2*(f1 - f1max))
    const float* __restrict__ f2,       // [H][N]
    const float* __restrict__ f1max,    // [H]
    float* __restrict__ anum,           // [N][256] numerator accumulator
    float* __restrict__ aden)           // [H][N]   denominator accumulator
{
    __shared__ __align__(16) _Float16 ea_lds[NHEAD][JW];   // 16 KB
    __shared__ __align__(16) _Float16 eb_lds[NHEAD][JW];   // 16 KB
    __shared__ __align__(4)  u8 abyte[TI][260];            // 16.6 KB padded

    const int itile = blockIdx.x >> 2;       // 0..127
    const int jwin  = blockIdx.x & 3;        // j-window
    const int i0    = itile * TI;
    const int J0    = jwin * JW;
    const int wv    = threadIdx.x >> 6;      // wave = head
    const int lane  = threadIdx.x & 63;
    const int col   = lane & 15;             // m (A) / n (B) / col (C)
    const int quad  = lane >> 4;

    // ---- Phase 1a: stage fp16 exp planes for this head's window ----
    {
        const _Float16* gea = EA16 + (size_t)wv * N_NODES + J0;
        const _Float16* geb = EB16 + (size_t)wv * N_NODES + J0;
        #pragma unroll
        for (int it = 0; it < 4; ++it) {
            const int off = it * 512 + lane * 8;
            *(float4*)&ea_lds[wv][off] = *(const float4*)(gea + off);
            *(float4*)&eb_lds[wv][off] = *(const float4*)(geb + off);
        }
    }
    // ---- Phase 1b: stage flag bytes (wave wv: 16 rows x 256 B) ----
    #pragma unroll
    for (int rr = 0; rr < 16; ++rr) {
        const int r = (wv << 4) + rr;
        *(unsigned*)&abyte[r][lane * 4] =
            gb32[(size_t)(i0 + r) * 256 + (J0 >> 5) + lane];
    }
    __syncthreads();

    // ---- Phase 2: fp16 flash j-loop, 4 i-subtiles ----
    const int h = wv;
    const float fm = f1max[h];
    h2 caH[NSUB], cbH[NSUB];
    float ls[NSUB];
    #pragma unroll
    for (int s = 0; s < NSUB; ++s) {
        const float f2i = f2[(size_t)h * N_NODES + i0 + s * 16 + col];
        const float g  = fm + f2i;
        const float mi = fmaxf(g, NEG * g);                 // leaky(g)
        const _Float16 ca = (_Float16)__expf(g - mi);
        const _Float16 cb = (_Float16)__expf(NEG * g - mi);
        caH[s][0] = ca; caH[s][1] = ca;
        cbH[s][0] = cb; cbH[s][1] = cb;
        ls[s] = 0.f;
    }
    const h2 ones = {(_Float16)1.0f, (_Float16)1.0f};

    const _Float16* sb = suppB + (size_t)h * 524288          // h*256*2048
                       + (size_t)(J0 >> 5) * 2048 + lane * 8;

    f32x4 acc[NSUB][4];
    #pragma unroll
    for (int s = 0; s < NSUB; ++s)
        #pragma unroll
        for (int t = 0; t < 4; ++t)
            acc[s][t] = (f32x4){0.f, 0.f, 0.f, 0.f};

    const int qo = quad << 3;

    #pragma unroll 2
    for (int jb = 0; jb < JW; jb += 32) {
        const int jl = jb + qo;                             // lane's local j
        const _Float16* fp = sb + (size_t)(jb >> 5) * 2048; // fragment base
        const half8 bv0 = *(const half8*)(fp);
        const half8 bv1 = *(const half8*)(fp + 512);
        const half8 bv2 = *(const half8*)(fp + 1024);
        const half8 bv3 = *(const half8*)(fp + 1536);

        union { half8 v; h2 pr[4]; } ea, eb;
        ea.v = *(const half8*)&ea_lds[h][jl];
        eb.v = *(const half8*)&eb_lds[h][jl];
        const int wo = (jb >> 3) + quad;                    // flag byte offset

        #pragma unroll
        for (int s = 0; s < NSUB; ++s) {
            const unsigned gw = abyte[col + s * 16][wo];
            union { half8 v; unsigned w[4]; h2 pr[4]; } af;
            #pragma unroll
            for (int p = 0; p < 4; ++p) {
                const h2 pa = ea.pr[p] * caH[s];            // v_pk_mul_f16
                const h2 pb = eb.pr[p] * cbH[s];
                const h2 x  = __builtin_elementwise_max(pa, pb); // v_pk_max
                const unsigned mlo = (unsigned)((int)(gw << (31 - 2 * p)) >> 31) & 0x0000FFFFu;
                const unsigned mhi = (unsigned)((int)(gw << (30 - 2 * p)) >> 31) & 0xFFFF0000u;
                union { h2 hh; unsigned u; } xu;
                xu.hh = x;
                xu.u &= (mlo | mhi);
                af.w[p] = xu.u;
                ls[s] = __builtin_amdgcn_fdot2(xu.hh, ones, ls[s], false);
            }
            acc[s][0] = __builtin_amdgcn_mfma_f32_16x16x32_f16(af.v, bv0, acc[s][0], 0, 0, 0);
            acc[s][1] = __builtin_amdgcn_mfma_f32_16x16x32_f16(af.v, bv1, acc[s][1], 0, 0, 0);
            acc[s][2] = __builtin_amdgcn_mfma_f32_16x16x32_f16(af.v, bv2, acc[s][2], 0, 0, 0);
            acc[s][3] = __builtin_amdgcn_mfma_f32_16x16x32_f16(af.v, bv3, acc[s][3], 0, 0, 0);
        }
    }

    // denominators: reduce over quads; lane L holds sum for i = L&15
    #pragma unroll
    for (int s = 0; s < NSUB; ++s) {
        ls[s] += __shfl_xor(ls[s], 16);
        ls[s] += __shfl_xor(ls[s], 32);
    }
    if (quad == 0) {
        #pragma unroll
        for (int s = 0; s < NSUB; ++s)
            unsafeAtomicAdd(aden + (size_t)h * N_NODES + i0 + s * 16 + col, ls[s]);
    }

    // numerators: C layout col=lane&15, row=quad*4+reg
    #pragma unroll
    for (int s = 0; s < NSUB; ++s) {
        #pragma unroll
        for (int reg = 0; reg < 4; ++reg) {
            const int irow = (quad << 2) + reg;
            float* ap = anum + (size_t)(i0 + s * 16 + irow) * HF + (h << 6) + col;
            #pragma unroll
            for (int t = 0; t < 4; ++t)
                unsafeAtomicAdd(ap + (t << 4), acc[s][t][reg]);
        }
    }
}

// ---------------------------------------------------------------------------
// K4: out += anum / aden   (denominator > 0 guaranteed by self-loops)
// ---------------------------------------------------------------------------
__global__ __launch_bounds__(256) void k_fin(const float* __restrict__ anum,
                                             const float* __restrict__ aden,
                                             float* __restrict__ out) {
    const int c = threadIdx.x;
    const int h = c >> 6;
    #pragma unroll
    for (int rr = 0; rr < 4; ++rr) {
        const int n = blockIdx.x * 4 + rr;
        out[(size_t)n * HF + c] += anum[(size_t)n * HF + c]
                                 / aden[(size_t)h * N_NODES + n];
    }
}

// ---------------------------------------------------------------------------
extern "C" void kernel_launch(void* const* d_in, const int* in_sizes, int n_in,
                              void* d_out, int out_size, void* d_ws, size_t ws_size,
                              hipStream_t stream) {
    const float* inp  = (const float*)d_in[0];  // [8192,256]
    const float* adj  = (const float*)d_in[1];  // [8192,8192]
    const float* W    = (const float*)d_in[2];  // [256,256]
    const float* U    = (const float*)d_in[3];  // [4,64,1]
    const float* V    = (const float*)d_in[4];  // [4,64,1]
    const float* Bias = (const float*)d_in[5];  // [1,256]
    const float* PW   = (const float*)d_in[6];  // [256,256]
    const float* PB   = (const float*)d_in[7];  // [256]
    float* out = (float*)d_out;                 // [8192,256] fp32

    char* ws = (char*)d_ws;
    _Float16* suppB = (_Float16*)(ws);                           // 4 MiB
    float* f1    = (float*)(ws + (4u << 20));                    // 128 KiB
    float* f2    = (float*)(ws + (4u << 20) + (128u << 10));     // 128 KiB
    float* f1mx  = (float*)(ws + (4u << 20) + (256u << 10));     // 64 B
    _Float16* EA16 = (_Float16*)(ws + (4u << 20) + (576u << 10));// 64 KiB
    _Float16* EB16 = (_Float16*)(ws + (4u << 20) + (704u << 10));// 64 KiB
    float* aden  = (float*)(ws + (4u << 20) + (832u << 10));     // 128 KiB
    u64*   gb64  = (u64*)(ws + (8u << 20));                      // 8 MiB
    _Float16* X16  = (_Float16*)(ws + (16u << 20));              // 4 MiB
    _Float16* W16B = (_Float16*)(ws + (20u << 20));              // 256 KiB
    float* anum  = (float*)(ws + (24u << 20));                   // 8 MiB

    k_x16  <<<2048, 256, 0, stream>>>(inp, X16, anum, aden);
    k_wpack<<<  64, 256, 0, stream>>>(W, PW, W16B);
    k_bits <<<2048, 256, 0, stream>>>(adj, gb64);
    k_gemm <<< 512, 256, 0, stream>>>(X16, W16B, U, V, Bias, PB,
                                      suppB, f1, f2, out);
    k_prep <<<NHEAD, 256, 0, stream>>>(f1, f1mx, EA16, EB16);
    k_attn_mfma<<<(N_NODES / TI) * JSPLIT_G, 256, 0, stream>>>(
        (const unsigned*)gb64, suppB, EA16, EB16, f2, f1mx, anum, aden);
    k_fin  <<<N_NODES / 4, 256, 0, stream>>>(anum, aden, out);
}

// Round 11
// 469.519 us; speedup vs baseline: 1.2665x; 1.0390x over previous
//
#include <hip/hip_runtime.h>
#include <hip/hip_bf16.h>

#define N_NODES 8192
#define IN_FEAT 256
#define OUT_F   64
#define NHEAD   4
#define HF      256     // NHEAD*OUT_F
#define NEG     0.2f

typedef unsigned short u16;
typedef unsigned char  u8;
typedef unsigned int   u32;
typedef unsigned long long u64;
typedef _Float16 h2    __attribute__((ext_vector_type(2)));
typedef _Float16 half8 __attribute__((ext_vector_type(8)));
typedef __attribute__((ext_vector_type(4))) float f32x4;    // MFMA C/D

// ---------------------------------------------------------------------------
// K_pre: X fp32->fp16, zero anum/aden, build fp16 MFMA-B fragments for the
//   256x512 weight block [W | PW^T]. (Former k_x16 + k_wpack, one launch.)
// ---------------------------------------------------------------------------
__global__ __launch_bounds__(256) void k_pre(const float* __restrict__ inp,
                                             const float* __restrict__ W,
                                             const float* __restrict__ PW,
                                             _Float16* __restrict__ X16,
                                             _Float16* __restrict__ W16B,
                                             float* __restrict__ anum,
                                             float* __restrict__ aden) {
    const int i = blockIdx.x * 256 + threadIdx.x;   // 0 .. 524287
    const float4 v = ((const float4*)inp)[i];
    union { _Float16 hh[4]; u64 q; } cv;
    cv.hh[0] = (_Float16)v.x; cv.hh[1] = (_Float16)v.y;
    cv.hh[2] = (_Float16)v.z; cv.hh[3] = (_Float16)v.w;
    ((u64*)X16)[i] = cv.q;
    ((float4*)anum)[i] = (float4){0.f, 0.f, 0.f, 0.f};
    if (i < 8192) ((float4*)aden)[i] = (float4){0.f, 0.f, 0.f, 0.f};

    if (i < 16384) {                     // weight fragment word i
        const int ks = i >> 11;          // k-step 0..7
        const int T  = (i >> 6) & 31;    // n-tile 0..31
        const int lane = i & 63;
        const int q  = lane >> 4, cc = lane & 15;
        const int n  = T * 16 + cc;
        const int k0 = ks * 32 + q * 8;
        union { _Float16 hh[8]; half8 v8; } o;
        #pragma unroll
        for (int e = 0; e < 8; ++e) {
            const int k = k0 + e;
            const float s = (n < 256) ? W[k * 256 + n]
                                      : PW[(size_t)(n - 256) * 256 + k];
            o.hh[e] = (_Float16)s;
        }
        *(half8*)(W16B + (size_t)i * 8) = o.v8;
    }
}

// ---------------------------------------------------------------------------
// K_gemm (MFMA): block = 16 rows x 512 cols ([supp | proj]), 4 waves, each
//   wave 16x128 (8 n-tiles) over K=256: 64 MFMAs/wave.
//   Waves 0-1: suppB in attn fragment layout (PACKED 8B stores: the 4 regs of
//   a quad are 4 consecutive j in one fragment word) + f1/f2 shfl reduce.
//   Waves 2-3: proj cols -> out = acc + Bias + PB.
// ---------------------------------------------------------------------------
#define GROWS 16
__global__ __launch_bounds__(256) void k_gemm(
    const _Float16* __restrict__ X16,   // [N][256] fp16
    const _Float16* __restrict__ W16B,  // [8][32][64][8] fp16 fragments
    const float* __restrict__ U,        // [256]
    const float* __restrict__ V,        // [256]
    const float* __restrict__ Bias,     // [256]
    const float* __restrict__ PB,       // [256]
    _Float16* __restrict__ suppB,       // [H][256][4][64][8] fp16 fragments
    float* __restrict__ f1,             // [H][N]
    float* __restrict__ f2,             // [H][N]
    float* __restrict__ outp)           // [N][256] proj + bias + proj_b
{
    __shared__ __align__(16) _Float16 xl[GROWS][264];   // 528B rows
    const int n0  = blockIdx.x * GROWS;
    const int tid = threadIdx.x;
    const int wv  = tid >> 6, lane = tid & 63;
    const int col = lane & 15, quad = lane >> 4;

    {
        const int r = tid >> 4, seg = tid & 15;
        const half8* src = (const half8*)(X16 + (size_t)(n0 + r) * 256 + seg * 16);
        *(half8*)&xl[r][seg * 16]     = src[0];
        *(half8*)&xl[r][seg * 16 + 8] = src[1];
    }
    __syncthreads();

    f32x4 acc[8];
    #pragma unroll
    for (int t = 0; t < 8; ++t) acc[t] = (f32x4){0.f, 0.f, 0.f, 0.f};

    const int qo = quad * 8;
    #pragma unroll
    for (int ks = 0; ks < 8; ++ks) {
        const half8 af = *(const half8*)&xl[col][ks * 32 + qo];
        const _Float16* bb = W16B + ((size_t)(ks * 32 + wv * 8) * 64 + lane) * 8;
        #pragma unroll
        for (int t = 0; t < 8; ++t) {
            const half8 bw = *(const half8*)(bb + (size_t)t * 512);
            acc[t] = __builtin_amdgcn_mfma_f32_16x16x32_f16(af, bw, acc[t], 0, 0, 0);
        }
    }

    if (wv < 2) {
        // ---- supp columns: packed fragment stores ----
        const int jbg  = n0 >> 5;
        const int nlo  = n0 & 31;
        const int jq   = nlo + quad * 4;       // 4 consecutive j (one word)
        const int e0   = jq & 7;               // 0 or 4
        const int wrow = (jq >> 3) << 4;
        #pragma unroll
        for (int t = 0; t < 8; ++t) {
            const int cg = wv * 128 + t * 16 + col;   // 0..255
            const int h  = cg >> 6;
            const int tp = (cg >> 4) & 3;
            union { _Float16 hh[4]; u64 q; } pk;
            #pragma unroll
            for (int reg = 0; reg < 4; ++reg) pk.hh[reg] = (_Float16)acc[t][reg];
            const size_t word = ((size_t)(h * 256 + jbg) * 4 + tp) * 64 + wrow + col;
            *(u64*)(suppB + word * 8 + e0) = pk.q;
        }
        // ---- f1/f2 head dots (heads wv*2, wv*2+1) ----
        float s1a[4] = {0,0,0,0}, s2a[4] = {0,0,0,0};
        float s1b[4] = {0,0,0,0}, s2b[4] = {0,0,0,0};
        #pragma unroll
        for (int t = 0; t < 8; ++t) {
            const int cg = wv * 128 + t * 16 + col;
            const float uu = U[cg], vv = V[cg];
            #pragma unroll
            for (int reg = 0; reg < 4; ++reg) {
                if (t < 4) { s1a[reg] += acc[t][reg] * uu; s2a[reg] += acc[t][reg] * vv; }
                else       { s1b[reg] += acc[t][reg] * uu; s2b[reg] += acc[t][reg] * vv; }
            }
        }
        #pragma unroll
        for (int m = 1; m < 16; m <<= 1) {
            #pragma unroll
            for (int reg = 0; reg < 4; ++reg) {
                s1a[reg] += __shfl_xor(s1a[reg], m);
                s2a[reg] += __shfl_xor(s2a[reg], m);
                s1b[reg] += __shfl_xor(s1b[reg], m);
                s2b[reg] += __shfl_xor(s2b[reg], m);
            }
        }
        if (col == 0) {
            const int hA = wv * 2, hB = wv * 2 + 1;
            #pragma unroll
            for (int reg = 0; reg < 4; ++reg) {
                const int n = n0 + quad * 4 + reg;
                f1[hA * N_NODES + n] = s1a[reg];
                f2[hA * N_NODES + n] = s2a[reg];
                f1[hB * N_NODES + n] = s1b[reg];
                f2[hB * N_NODES + n] = s2b[reg];
            }
        }
    } else {
        // ---- proj columns ----
        #pragma unroll
        for (int t = 0; t < 8; ++t) {
            const int cg = (wv - 2) * 128 + t * 16 + col;
            const float bb2 = Bias[cg] + PB[cg];
            #pragma unroll
            for (int reg = 0; reg < 4; ++reg) {
                const int irow = quad * 4 + reg;
                outp[(size_t)(n0 + irow) * HF + cg] = acc[t][reg] + bb2;
            }
        }
    }
}

// ---------------------------------------------------------------------------
// K2: per-head f1 max + fp16 factored-exponential planes.
// ---------------------------------------------------------------------------
__global__ __launch_bounds__(256) void k_prep(const float* __restrict__ f1,
                                              float* __restrict__ f1max,
                                              _Float16* __restrict__ EA16,
                                              _Float16* __restrict__ EB16) {
    __shared__ float red[256];
    const int h = blockIdx.x;
    float m = -1e30f;
    for (int j = threadIdx.x; j < N_NODES; j += 256)
        m = fmaxf(m, f1[h * N_NODES + j]);
    red[threadIdx.x] = m;
    __syncthreads();
    for (int s = 128; s > 0; s >>= 1) {
        if (threadIdx.x < s) red[threadIdx.x] = fmaxf(red[threadIdx.x], red[threadIdx.x + s]);
        __syncthreads();
    }
    const float fm = red[0];
    if (threadIdx.x == 0) f1max[h] = fm;
    for (int j = threadIdx.x; j < N_NODES; j += 256) {
        const float d = f1[h * N_NODES + j] - fm;
        EA16[(size_t)h * N_NODES + j] = (_Float16)__expf(d);
        EB16[(size_t)h * N_NODES + j] = (_Float16)__expf(NEG * d);
    }
}

// ---------------------------------------------------------------------------
// K3: MFMA attention with FUSED adjacency pack. Each block reads its own
//   64x2048 fp32 adj window (512 KB; blocks disjoint -> adj read exactly once
//   across the grid) and packs straight-bit flags into LDS in phase 1b.
//   The ~42us adj HBM stream now overlaps resident blocks' compute instead of
//   standing as a serial k_bits dispatch. Rest identical to round 10.
// ---------------------------------------------------------------------------
#define TI 64
#define NSUB 4
#define JSPLIT_G 4
#define JW (N_NODES / JSPLIT_G)     // 2048-j window per block

__global__ __launch_bounds__(256, 3) void k_attn_mfma(
    const float* __restrict__ adj,      // [N][N] fp32
    const _Float16* __restrict__ suppB, // [H][256][4][64][8] fp16 fragments
    const _Float16* __restrict__ EA16,  // [H][N] fp16 exp(f1 - f1max)
    const _Float16* __restrict__ EB16,  // [H][N] fp16 exp(0.2*(f1 - f1max))
    const float* __restrict__ f2,       // [H][N]
    const float* __restrict__ f1max,    // [H]
    float* __restrict__ anum,           // [N][256] numerator accumulator
    float* __restrict__ aden)           // [H][N]   denominator accumulator
{
    __shared__ __align__(16) _Float16 ea_lds[NHEAD][JW];   // 16 KB
    __shared__ __align__(16) _Float16 eb_lds[NHEAD][JW];   // 16 KB
    __shared__ __align__(4)  u8 abyte[TI][260];            // 16.6 KB padded

    const int itile = blockIdx.x >> 2;       // 0..127
    const int jwin  = blockIdx.x & 3;        // j-window
    const int i0    = itile * TI;
    const int J0    = jwin * JW;
    const int wv    = threadIdx.x >> 6;      // wave = head
    const int lane  = threadIdx.x & 63;
    const int col   = lane & 15;             // m (A) / n (B) / col (C)
    const int quad  = lane >> 4;

    // ---- Phase 1a: stage fp16 exp planes for this head's window ----
    {
        const _Float16* gea = EA16 + (size_t)wv * N_NODES + J0;
        const _Float16* geb = EB16 + (size_t)wv * N_NODES + J0;
        #pragma unroll
        for (int it = 0; it < 4; ++it) {
            const int off = it * 512 + lane * 8;
            *(float4*)&ea_lds[wv][off] = *(const float4*)(gea + off);
            *(float4*)&eb_lds[wv][off] = *(const float4*)(geb + off);
        }
    }
    // ---- Phase 1b: pack adj window bits (wave wv: 16 rows) ----
    //   lane covers cols [lane*32, lane*32+32): 8 float4 -> one u32 of
    //   straight-order bits (bit k of byte b <-> j = 8b+k).
    #pragma unroll 2
    for (int rr = 0; rr < 16; ++rr) {
        const int r = (wv << 4) + rr;
        const float* ar = adj + (size_t)(i0 + r) * N_NODES + J0 + lane * 32;
        unsigned wrd = 0;
        #pragma unroll
        for (int p = 0; p < 8; ++p) {
            const float4 a = *(const float4*)(ar + p * 4);
            const unsigned nib =
                (unsigned)(a.x != 0.f)        | ((unsigned)(a.y != 0.f) << 1) |
                ((unsigned)(a.z != 0.f) << 2) | ((unsigned)(a.w != 0.f) << 3);
            wrd |= nib << (p * 4);
        }
        *(unsigned*)&abyte[r][lane * 4] = wrd;
    }
    __syncthreads();

    // ---- Phase 2: fp16 flash j-loop, 4 i-subtiles ----
    const int h = wv;
    const float fm = f1max[h];
    h2 caH[NSUB], cbH[NSUB];
    float ls[NSUB];
    #pragma unroll
    for (int s = 0; s < NSUB; ++s) {
        const float f2i = f2[(size_t)h * N_NODES + i0 + s * 16 + col];
        const float g  = fm + f2i;
        const float mi = fmaxf(g, NEG * g);                 // leaky(g)
        const _Float16 ca = (_Float16)__expf(g - mi);
        const _Float16 cb = (_Float16)__expf(NEG * g - mi);
        caH[s][0] = ca; caH[s][1] = ca;
        cbH[s][0] = cb; cbH[s][1] = cb;
        ls[s] = 0.f;
    }
    const h2 ones = {(_Float16)1.0f, (_Float16)1.0f};

    const _Float16* sb = suppB + (size_t)h * 524288          // h*256*2048
                       + (size_t)(J0 >> 5) * 2048 + lane * 8;

    f32x4 acc[NSUB][4];
    #pragma unroll
    for (int s = 0; s < NSUB; ++s)
        #pragma unroll
        for (int t = 0; t < 4; ++t)
            acc[s][t] = (f32x4){0.f, 0.f, 0.f, 0.f};

    const int qo = quad << 3;

    #pragma unroll 2
    for (int jb = 0; jb < JW; jb += 32) {
        const int jl = jb + qo;                             // lane's local j
        const _Float16* fp = sb + (size_t)(jb >> 5) * 2048; // fragment base
        const half8 bv0 = *(const half8*)(fp);
        const half8 bv1 = *(const half8*)(fp + 512);
        const half8 bv2 = *(const half8*)(fp + 1024);
        const half8 bv3 = *(const half8*)(fp + 1536);

        union { half8 v; h2 pr[4]; } ea, eb;
        ea.v = *(const half8*)&ea_lds[h][jl];
        eb.v = *(const half8*)&eb_lds[h][jl];
        const int wo = (jb >> 3) + quad;                    // flag byte offset

        #pragma unroll
        for (int s = 0; s < NSUB; ++s) {
            const unsigned gw = abyte[col + s * 16][wo];
            union { half8 v; unsigned w[4]; h2 pr[4]; } af;
            #pragma unroll
            for (int p = 0; p < 4; ++p) {
                const h2 pa = ea.pr[p] * caH[s];            // v_pk_mul_f16
                const h2 pb = eb.pr[p] * cbH[s];
                const h2 x  = __builtin_elementwise_max(pa, pb); // v_pk_max
                const unsigned mlo = (unsigned)((int)(gw << (31 - 2 * p)) >> 31) & 0x0000FFFFu;
                const unsigned mhi = (unsigned)((int)(gw << (30 - 2 * p)) >> 31) & 0xFFFF0000u;
                union { h2 hh; unsigned u; } xu;
                xu.hh = x;
                xu.u &= (mlo | mhi);
                af.w[p] = xu.u;
                ls[s] = __builtin_amdgcn_fdot2(xu.hh, ones, ls[s], false);
            }
            acc[s][0] = __builtin_amdgcn_mfma_f32_16x16x32_f16(af.v, bv0, acc[s][0], 0, 0, 0);
            acc[s][1] = __builtin_amdgcn_mfma_f32_16x16x32_f16(af.v, bv1, acc[s][1], 0, 0, 0);
            acc[s][2] = __builtin_amdgcn_mfma_f32_16x16x32_f16(af.v, bv2, acc[s][2], 0, 0, 0);
            acc[s][3] = __builtin_amdgcn_mfma_f32_16x16x32_f16(af.v, bv3, acc[s][3], 0, 0, 0);
        }
    }

    // denominators: reduce over quads; lane L holds sum for i = L&15
    #pragma unroll
    for (int s = 0; s < NSUB; ++s) {
        ls[s] += __shfl_xor(ls[s], 16);
        ls[s] += __shfl_xor(ls[s], 32);
    }
    if (quad == 0) {
        #pragma unroll
        for (int s = 0; s < NSUB; ++s)
            unsafeAtomicAdd(aden + (size_t)h * N_NODES + i0 + s * 16 + col, ls[s]);
    }

    // numerators: C layout col=lane&15, row=quad*4+reg
    #pragma unroll
    for (int s = 0; s < NSUB; ++s) {
        #pragma unroll
        for (int reg = 0; reg < 4; ++reg) {
            const int irow = (quad << 2) + reg;
            float* ap = anum + (size_t)(i0 + s * 16 + irow) * HF + (h << 6) + col;
            #pragma unroll
            for (int t = 0; t < 4; ++t)
                unsafeAtomicAdd(ap + (t << 4), acc[s][t][reg]);
        }
    }
}

// ---------------------------------------------------------------------------
// K4: out += anum / aden   (denominator > 0 guaranteed by self-loops)
// ---------------------------------------------------------------------------
__global__ __launch_bounds__(256) void k_fin(const float* __restrict__ anum,
                                             const float* __restrict__ aden,
                                             float* __restrict__ out) {
    const int c = threadIdx.x;
    const int h = c >> 6;
    #pragma unroll
    for (int rr = 0; rr < 4; ++rr) {
        const int n = blockIdx.x * 4 + rr;
        out[(size_t)n * HF + c] += anum[(size_t)n * HF + c]
                                 / aden[(size_t)h * N_NODES + n];
    }
}

// ---------------------------------------------------------------------------
extern "C" void kernel_launch(void* const* d_in, const int* in_sizes, int n_in,
                              void* d_out, int out_size, void* d_ws, size_t ws_size,
                              hipStream_t stream) {
    const float* inp  = (const float*)d_in[0];  // [8192,256]
    const float* adj  = (const float*)d_in[1];  // [8192,8192]
    const float* W    = (const float*)d_in[2];  // [256,256]
    const float* U    = (const float*)d_in[3];  // [4,64,1]
    const float* V    = (const float*)d_in[4];  // [4,64,1]
    const float* Bias = (const float*)d_in[5];  // [1,256]
    const float* PW   = (const float*)d_in[6];  // [256,256]
    const float* PB   = (const float*)d_in[7];  // [256]
    float* out = (float*)d_out;                 // [8192,256] fp32

    char* ws = (char*)d_ws;
    _Float16* suppB = (_Float16*)(ws);                           // 4 MiB
    float* f1    = (float*)(ws + (4u << 20));                    // 128 KiB
    float* f2    = (float*)(ws + (4u << 20) + (128u << 10));     // 128 KiB
    float* f1mx  = (float*)(ws + (4u << 20) + (256u << 10));     // 64 B
    _Float16* EA16 = (_Float16*)(ws + (4u << 20) + (576u << 10));// 64 KiB
    _Float16* EB16 = (_Float16*)(ws + (4u << 20) + (704u << 10));// 64 KiB
    float* aden  = (float*)(ws + (4u << 20) + (832u << 10));     // 128 KiB
    _Float16* X16  = (_Float16*)(ws + (16u << 20));              // 4 MiB
    _Float16* W16B = (_Float16*)(ws + (20u << 20));              // 256 KiB
    float* anum  = (float*)(ws + (24u << 20));                   // 8 MiB

    k_pre  <<<2048, 256, 0, stream>>>(inp, W, PW, X16, W16B, anum, aden);
    k_gemm <<< 512, 256, 0, stream>>>(X16, W16B, U, V, Bias, PB,
                                      suppB, f1, f2, out);
    k_prep <<<NHEAD, 256, 0, stream>>>(f1, f1mx, EA16, EB16);
    k_attn_mfma<<<(N_NODES / TI) * JSPLIT_G, 256, 0, stream>>>(
        adj, suppB, EA16, EB16, f2, f1mx, anum, aden);
    k_fin  <<<N_NODES / 4, 256, 0, stream>>>(anum, aden, out);
}

// Round 12
// 454.161 us; speedup vs baseline: 1.3094x; 1.0338x over previous
//
#include <hip/hip_runtime.h>
#include <hip/hip_bf16.h>

#define N_NODES 8192
#define IN_FEAT 256
#define OUT_F   64
#define NHEAD   4
#define HF      256     // NHEAD*OUT_F
#define NEG     0.2f

typedef unsigned short u16;
typedef unsigned char  u8;
typedef unsigned int   u32;
typedef unsigned long long u64;
typedef _Float16 h2    __attribute__((ext_vector_type(2)));
typedef _Float16 half8 __attribute__((ext_vector_type(8)));
typedef __attribute__((ext_vector_type(4))) float f32x4;    // MFMA C/D

// ---------------------------------------------------------------------------
// K_wpack: fp16 MFMA-B fragments for the 256x512 weight block [W | PW^T].
// ---------------------------------------------------------------------------
__global__ __launch_bounds__(256) void k_wpack(const float* __restrict__ W,
                                               const float* __restrict__ PW,
                                               _Float16* __restrict__ W16B) {
    const int i = blockIdx.x * 256 + threadIdx.x;   // word 0..16383
    const int ks = i >> 11;            // k-step 0..7
    const int T  = (i >> 6) & 31;      // n-tile 0..31
    const int lane = i & 63;
    const int q  = lane >> 4, cc = lane & 15;
    const int n  = T * 16 + cc;
    const int k0 = ks * 32 + q * 8;
    union { _Float16 hh[8]; half8 v8; } o;
    #pragma unroll
    for (int e = 0; e < 8; ++e) {
        const int k = k0 + e;
        const float s = (n < 256) ? W[k * 256 + n]
                                  : PW[(size_t)(n - 256) * 256 + k];
        o.hh[e] = (_Float16)s;
    }
    *(half8*)(W16B + (size_t)i * 8) = o.v8;
}

// ---------------------------------------------------------------------------
// K_gemm (MFMA): block = 16 rows x 512 cols ([supp | proj]), 4 waves.
//   Stages inp fp32 -> fp16 LDS directly (no X16 buffer), zeroes its rows of
//   anum/aden in the epilogue. Waves 0-1: suppB fragments + f1/f2 reduce.
//   Waves 2-3: proj cols -> out = acc + Bias + PB.
// ---------------------------------------------------------------------------
#define GROWS 16
__global__ __launch_bounds__(256) void k_gemm(
    const float* __restrict__ inp,      // [N][256] fp32
    const _Float16* __restrict__ W16B,  // [8][32][64][8] fp16 fragments
    const float* __restrict__ U,        // [256]
    const float* __restrict__ V,        // [256]
    const float* __restrict__ Bias,     // [256]
    const float* __restrict__ PB,       // [256]
    _Float16* __restrict__ suppB,       // [H][256][4][64][8] fp16 fragments
    float* __restrict__ f1,             // [H][N]
    float* __restrict__ f2,             // [H][N]
    float* __restrict__ outp,           // [N][256] proj + bias + proj_b
    float* __restrict__ anum,           // [N][256]  zeroed here
    float* __restrict__ aden)           // [H][N]    zeroed here
{
    __shared__ __align__(16) _Float16 xl[GROWS][264];   // 528B rows
    const int n0  = blockIdx.x * GROWS;
    const int tid = threadIdx.x;
    const int wv  = tid >> 6, lane = tid & 63;
    const int col = lane & 15, quad = lane >> 4;

    // stage + convert: thread handles 16 floats of one row
    {
        const int r = tid >> 4, seg = tid & 15;
        const float* src = inp + (size_t)(n0 + r) * 256 + seg * 16;
        const float4 v0 = *(const float4*)(src);
        const float4 v1 = *(const float4*)(src + 4);
        const float4 v2 = *(const float4*)(src + 8);
        const float4 v3 = *(const float4*)(src + 12);
        union { _Float16 hh[8]; half8 v; } c0, c1;
        c0.hh[0] = (_Float16)v0.x; c0.hh[1] = (_Float16)v0.y;
        c0.hh[2] = (_Float16)v0.z; c0.hh[3] = (_Float16)v0.w;
        c0.hh[4] = (_Float16)v1.x; c0.hh[5] = (_Float16)v1.y;
        c0.hh[6] = (_Float16)v1.z; c0.hh[7] = (_Float16)v1.w;
        c1.hh[0] = (_Float16)v2.x; c1.hh[1] = (_Float16)v2.y;
        c1.hh[2] = (_Float16)v2.z; c1.hh[3] = (_Float16)v2.w;
        c1.hh[4] = (_Float16)v3.x; c1.hh[5] = (_Float16)v3.y;
        c1.hh[6] = (_Float16)v3.z; c1.hh[7] = (_Float16)v3.w;
        *(half8*)&xl[r][seg * 16]     = c0.v;
        *(half8*)&xl[r][seg * 16 + 8] = c1.v;
    }
    __syncthreads();

    f32x4 acc[8];
    #pragma unroll
    for (int t = 0; t < 8; ++t) acc[t] = (f32x4){0.f, 0.f, 0.f, 0.f};

    const int qo = quad * 8;
    #pragma unroll
    for (int ks = 0; ks < 8; ++ks) {
        const half8 af = *(const half8*)&xl[col][ks * 32 + qo];
        const _Float16* bb = W16B + ((size_t)(ks * 32 + wv * 8) * 64 + lane) * 8;
        #pragma unroll
        for (int t = 0; t < 8; ++t) {
            const half8 bw = *(const half8*)(bb + (size_t)t * 512);
            acc[t] = __builtin_amdgcn_mfma_f32_16x16x32_f16(af, bw, acc[t], 0, 0, 0);
        }
    }

    if (wv < 2) {
        // ---- supp columns: packed fragment stores ----
        const int jbg  = n0 >> 5;
        const int nlo  = n0 & 31;
        const int jq   = nlo + quad * 4;       // 4 consecutive j (one word)
        const int e0   = jq & 7;               // 0 or 4
        const int wrow = (jq >> 3) << 4;
        #pragma unroll
        for (int t = 0; t < 8; ++t) {
            const int cg = wv * 128 + t * 16 + col;   // 0..255
            const int h  = cg >> 6;
            const int tp = (cg >> 4) & 3;
            union { _Float16 hh[4]; u64 q; } pk;
            #pragma unroll
            for (int reg = 0; reg < 4; ++reg) pk.hh[reg] = (_Float16)acc[t][reg];
            const size_t word = ((size_t)(h * 256 + jbg) * 4 + tp) * 64 + wrow + col;
            *(u64*)(suppB + word * 8 + e0) = pk.q;
        }
        // ---- f1/f2 head dots (heads wv*2, wv*2+1) ----
        float s1a[4] = {0,0,0,0}, s2a[4] = {0,0,0,0};
        float s1b[4] = {0,0,0,0}, s2b[4] = {0,0,0,0};
        #pragma unroll
        for (int t = 0; t < 8; ++t) {
            const int cg = wv * 128 + t * 16 + col;
            const float uu = U[cg], vv = V[cg];
            #pragma unroll
            for (int reg = 0; reg < 4; ++reg) {
                if (t < 4) { s1a[reg] += acc[t][reg] * uu; s2a[reg] += acc[t][reg] * vv; }
                else       { s1b[reg] += acc[t][reg] * uu; s2b[reg] += acc[t][reg] * vv; }
            }
        }
        #pragma unroll
        for (int m = 1; m < 16; m <<= 1) {
            #pragma unroll
            for (int reg = 0; reg < 4; ++reg) {
                s1a[reg] += __shfl_xor(s1a[reg], m);
                s2a[reg] += __shfl_xor(s2a[reg], m);
                s1b[reg] += __shfl_xor(s1b[reg], m);
                s2b[reg] += __shfl_xor(s2b[reg], m);
            }
        }
        if (col == 0) {
            const int hA = wv * 2, hB = wv * 2 + 1;
            #pragma unroll
            for (int reg = 0; reg < 4; ++reg) {
                const int n = n0 + quad * 4 + reg;
                f1[hA * N_NODES + n] = s1a[reg];
                f2[hA * N_NODES + n] = s2a[reg];
                f1[hB * N_NODES + n] = s1b[reg];
                f2[hB * N_NODES + n] = s2b[reg];
            }
        }
    } else {
        // ---- proj columns ----
        #pragma unroll
        for (int t = 0; t < 8; ++t) {
            const int cg = (wv - 2) * 128 + t * 16 + col;
            const float bb2 = Bias[cg] + PB[cg];
            #pragma unroll
            for (int reg = 0; reg < 4; ++reg) {
                const int irow = quad * 4 + reg;
                outp[(size_t)(n0 + irow) * HF + cg] = acc[t][reg] + bb2;
            }
        }
    }

    // ---- epilogue: zero this block's rows of anum/aden ----
    {
        const float4 z = {0.f, 0.f, 0.f, 0.f};
        float4* an = (float4*)(anum + (size_t)(n0 + (tid >> 4)) * HF + (tid & 15) * 16);
        an[0] = z; an[1] = z; an[2] = z; an[3] = z;
        if (tid < 64)
            aden[(size_t)(tid >> 4) * N_NODES + n0 + (tid & 15)] = 0.f;
    }
}

// ---------------------------------------------------------------------------
// K2: per-head f1 max + fp16 factored-exponential planes.
// ---------------------------------------------------------------------------
__global__ __launch_bounds__(256) void k_prep(const float* __restrict__ f1,
                                              float* __restrict__ f1max,
                                              _Float16* __restrict__ EA16,
                                              _Float16* __restrict__ EB16) {
    __shared__ float red[256];
    const int h = blockIdx.x;
    float m = -1e30f;
    for (int j = threadIdx.x; j < N_NODES; j += 256)
        m = fmaxf(m, f1[h * N_NODES + j]);
    red[threadIdx.x] = m;
    __syncthreads();
    for (int s = 128; s > 0; s >>= 1) {
        if (threadIdx.x < s) red[threadIdx.x] = fmaxf(red[threadIdx.x], red[threadIdx.x + s]);
        __syncthreads();
    }
    const float fm = red[0];
    if (threadIdx.x == 0) f1max[h] = fm;
    for (int j = threadIdx.x; j < N_NODES; j += 256) {
        const float d = f1[h * N_NODES + j] - fm;
        EA16[(size_t)h * N_NODES + j] = (_Float16)__expf(d);
        EB16[(size_t)h * N_NODES + j] = (_Float16)__expf(NEG * d);
    }
}

// ---------------------------------------------------------------------------
// K3: MFMA attention. JSPLIT=8 (grid 1024 -> 4 blocks/CU; round 11 was
//   grid-limited at 2). LDS = flags only (8.7 KB): EA/EB planes are 16 KB
//   L2-resident broadcasts, read directly as dense half8. Fused adj pack
//   (64x1024 fp32 window per block, disjoint across grid).
// ---------------------------------------------------------------------------
#define TI 64
#define NSUB 4
#define JSPLIT_G 8
#define JW (N_NODES / JSPLIT_G)     // 1024-j window per block
#define ABW 132                     // bytes per row (128 + 4 pad): 33 dwords

__global__ __launch_bounds__(256, 4) void k_attn_mfma(
    const float* __restrict__ adj,      // [N][N] fp32
    const _Float16* __restrict__ suppB, // [H][256][4][64][8] fp16 fragments
    const _Float16* __restrict__ EA16,  // [H][N] fp16 exp(f1 - f1max)
    const _Float16* __restrict__ EB16,  // [H][N] fp16 exp(0.2*(f1 - f1max))
    const float* __restrict__ f2,       // [H][N]
    const float* __restrict__ f1max,    // [H]
    float* __restrict__ anum,           // [N][256] numerator accumulator
    float* __restrict__ aden)           // [H][N]   denominator accumulator
{
    __shared__ __align__(4) u8 abyte[TI][ABW];   // 8.4 KB

    const int itile = blockIdx.x >> 3;       // 0..127
    const int jwin  = blockIdx.x & 7;        // j-window
    const int i0    = itile * TI;
    const int J0    = jwin * JW;
    const int wv    = threadIdx.x >> 6;      // wave = head
    const int lane  = threadIdx.x & 63;
    const int col   = lane & 15;             // m (A) / n (B) / col (C)
    const int quad  = lane >> 4;

    // ---- Phase 1: pack adj window bits (wave wv: 16 rows, 2 rows/pass) ----
    //   lanes 0-31 pack row r, word w=lane&31 covering j [32w, 32w+32).
    #pragma unroll
    for (int pass = 0; pass < 8; ++pass) {
        const int r = (wv << 4) + pass * 2 + (lane >> 5);
        const int w = lane & 31;
        const float* ar = adj + (size_t)(i0 + r) * N_NODES + J0 + w * 32;
        unsigned wrd = 0;
        #pragma unroll
        for (int p = 0; p < 8; ++p) {
            const float4 a = *(const float4*)(ar + p * 4);
            const unsigned nib =
                (unsigned)(a.x != 0.f)        | ((unsigned)(a.y != 0.f) << 1) |
                ((unsigned)(a.z != 0.f) << 2) | ((unsigned)(a.w != 0.f) << 3);
            wrd |= nib << (p * 4);
        }
        *(unsigned*)&abyte[r][w * 4] = wrd;
    }
    __syncthreads();

    // ---- Phase 2: fp16 flash j-loop, 4 i-subtiles ----
    const int h = wv;
    const float fm = f1max[h];
    h2 caH[NSUB], cbH[NSUB];
    float ls[NSUB];
    #pragma unroll
    for (int s = 0; s < NSUB; ++s) {
        const float f2i = f2[(size_t)h * N_NODES + i0 + s * 16 + col];
        const float g  = fm + f2i;
        const float mi = fmaxf(g, NEG * g);                 // leaky(g)
        const _Float16 ca = (_Float16)__expf(g - mi);
        const _Float16 cb = (_Float16)__expf(NEG * g - mi);
        caH[s][0] = ca; caH[s][1] = ca;
        cbH[s][0] = cb; cbH[s][1] = cb;
        ls[s] = 0.f;
    }
    const h2 ones = {(_Float16)1.0f, (_Float16)1.0f};

    const _Float16* gea = EA16 + (size_t)h * N_NODES + J0;
    const _Float16* geb = EB16 + (size_t)h * N_NODES + J0;
    const _Float16* sb  = suppB + (size_t)h * 524288          // h*256*2048
                        + (size_t)(J0 >> 5) * 2048 + lane * 8;

    f32x4 acc[NSUB][4];
    #pragma unroll
    for (int s = 0; s < NSUB; ++s)
        #pragma unroll
        for (int t = 0; t < 4; ++t)
            acc[s][t] = (f32x4){0.f, 0.f, 0.f, 0.f};

    const int qo = quad << 3;

    #pragma unroll 2
    for (int jb = 0; jb < JW; jb += 32) {
        const int jl = jb + qo;                             // lane's local j
        const _Float16* fp = sb + (size_t)(jb >> 5) * 2048; // fragment base
        const half8 bv0 = *(const half8*)(fp);
        const half8 bv1 = *(const half8*)(fp + 512);
        const half8 bv2 = *(const half8*)(fp + 1024);
        const half8 bv3 = *(const half8*)(fp + 1536);

        union { half8 v; h2 pr[4]; } ea, eb;
        ea.v = *(const half8*)(gea + jl);
        eb.v = *(const half8*)(geb + jl);
        const int wo = (jb >> 3) + quad;                    // flag byte offset

        #pragma unroll
        for (int s = 0; s < NSUB; ++s) {
            const unsigned gw = abyte[col + s * 16][wo];
            union { half8 v; unsigned w[4]; h2 pr[4]; } af;
            #pragma unroll
            for (int p = 0; p < 4; ++p) {
                const h2 pa = ea.pr[p] * caH[s];            // v_pk_mul_f16
                const h2 pb = eb.pr[p] * cbH[s];
                const h2 x  = __builtin_elementwise_max(pa, pb); // v_pk_max
                const unsigned mlo = (unsigned)((int)(gw << (31 - 2 * p)) >> 31) & 0x0000FFFFu;
                const unsigned mhi = (unsigned)((int)(gw << (30 - 2 * p)) >> 31) & 0xFFFF0000u;
                union { h2 hh; unsigned u; } xu;
                xu.hh = x;
                xu.u &= (mlo | mhi);
                af.w[p] = xu.u;
                ls[s] = __builtin_amdgcn_fdot2(xu.hh, ones, ls[s], false);
            }
            acc[s][0] = __builtin_amdgcn_mfma_f32_16x16x32_f16(af.v, bv0, acc[s][0], 0, 0, 0);
            acc[s][1] = __builtin_amdgcn_mfma_f32_16x16x32_f16(af.v, bv1, acc[s][1], 0, 0, 0);
            acc[s][2] = __builtin_amdgcn_mfma_f32_16x16x32_f16(af.v, bv2, acc[s][2], 0, 0, 0);
            acc[s][3] = __builtin_amdgcn_mfma_f32_16x16x32_f16(af.v, bv3, acc[s][3], 0, 0, 0);
        }
    }

    // denominators: reduce over quads; lane L holds sum for i = L&15
    #pragma unroll
    for (int s = 0; s < NSUB; ++s) {
        ls[s] += __shfl_xor(ls[s], 16);
        ls[s] += __shfl_xor(ls[s], 32);
    }
    if (quad == 0) {
        #pragma unroll
        for (int s = 0; s < NSUB; ++s)
            unsafeAtomicAdd(aden + (size_t)h * N_NODES + i0 + s * 16 + col, ls[s]);
    }

    // numerators: C layout col=lane&15, row=quad*4+reg
    #pragma unroll
    for (int s = 0; s < NSUB; ++s) {
        #pragma unroll
        for (int reg = 0; reg < 4; ++reg) {
            const int irow = (quad << 2) + reg;
            float* ap = anum + (size_t)(i0 + s * 16 + irow) * HF + (h << 6) + col;
            #pragma unroll
            for (int t = 0; t < 4; ++t)
                unsafeAtomicAdd(ap + (t << 4), acc[s][t][reg]);
        }
    }
}

// ---------------------------------------------------------------------------
// K4: out += anum / aden   (denominator > 0 guaranteed by self-loops)
// ---------------------------------------------------------------------------
__global__ __launch_bounds__(256) void k_fin(const float* __restrict__ anum,
                                             const float* __restrict__ aden,
                                             float* __restrict__ out) {
    const int c = threadIdx.x;
    const int h = c >> 6;
    #pragma unroll
    for (int rr = 0; rr < 4; ++rr) {
        const int n = blockIdx.x * 4 + rr;
        out[(size_t)n * HF + c] += anum[(size_t)n * HF + c]
                                 / aden[(size_t)h * N_NODES + n];
    }
}

// ---------------------------------------------------------------------------
extern "C" void kernel_launch(void* const* d_in, const int* in_sizes, int n_in,
                              void* d_out, int out_size, void* d_ws, size_t ws_size,
                              hipStream_t stream) {
    const float* inp  = (const float*)d_in[0];  // [8192,256]
    const float* adj  = (const float*)d_in[1];  // [8192,8192]
    const float* W    = (const float*)d_in[2];  // [256,256]
    const float* U    = (const float*)d_in[3];  // [4,64,1]
    const float* V    = (const float*)d_in[4];  // [4,64,1]
    const float* Bias = (const float*)d_in[5];  // [1,256]
    const float* PW   = (const float*)d_in[6];  // [256,256]
    const float* PB   = (const float*)d_in[7];  // [256]
    float* out = (float*)d_out;                 // [8192,256] fp32

    char* ws = (char*)d_ws;
    _Float16* suppB = (_Float16*)(ws);                           // 4 MiB
    float* f1    = (float*)(ws + (4u << 20));                    // 128 KiB
    float* f2    = (float*)(ws + (4u << 20) + (128u << 10));     // 128 KiB
    float* f1mx  = (float*)(ws + (4u << 20) + (256u << 10));     // 64 B
    _Float16* EA16 = (_Float16*)(ws + (4u << 20) + (576u << 10));// 64 KiB
    _Float16* EB16 = (_Float16*)(ws + (4u << 20) + (704u << 10));// 64 KiB
    float* aden  = (float*)(ws + (4u << 20) + (832u << 10));     // 128 KiB
    _Float16* W16B = (_Float16*)(ws + (20u << 20));              // 256 KiB
    float* anum  = (float*)(ws + (24u << 20));                   // 8 MiB

    k_wpack<<<  64, 256, 0, stream>>>(W, PW, W16B);
    k_gemm <<< 512, 256, 0, stream>>>(inp, W16B, U, V, Bias, PB,
                                      suppB, f1, f2, out, anum, aden);
    k_prep <<<NHEAD, 256, 0, stream>>>(f1, f1mx, EA16, EB16);
    k_attn_mfma<<<(N_NODES / TI) * JSPLIT_G, 256, 0, stream>>>(
        adj, suppB, EA16, EB16, f2, f1mx, anum, aden);
    k_fin  <<<N_NODES / 4, 256, 0, stream>>>(anum, aden, out);
}